// Round 7
// baseline (408.838 us; speedup 1.0000x reference)
//
#include <hip/hip_runtime.h>
#include <stdint.h>

typedef uint16_t u16;
typedef uint32_t u32;

typedef __attribute__((ext_vector_type(8))) short bf16x8;
typedef __attribute__((ext_vector_type(4))) float f32x4;

typedef __attribute__((address_space(1))) const u32 gas_u32;
typedef __attribute__((address_space(3))) u32 las_u32;

#define S_LEN 4096
#define HDIM  256
#define FFDIM 1024

__device__ __forceinline__ float bf2f(u16 u) { return __uint_as_float(((u32)u) << 16); }
__device__ __forceinline__ u16 f2bf(float f) {
  u32 x = __float_as_uint(f);
  return (u16)((x + 0x7fffu + ((x >> 16) & 1u)) >> 16);
}
__device__ __forceinline__ float gelu_f(float x) {
  return 0.5f * x * (1.0f + erff(x * 0.7071067811865475f));
}
__device__ __forceinline__ void glds16(const u16* g, u16* l) {
  __builtin_amdgcn_global_load_lds((gas_u32*)g, (las_u32*)l, 16, 0, 0);
}

// ---------------- zero guard rows of padded buffers ----------------
__global__ __launch_bounds__(256) void zero_guards(uint4* __restrict__ xn2p, uint4* __restrict__ f1p) {
  int t = blockIdx.x * 256 + threadIdx.x;
  const uint4 z = {0u, 0u, 0u, 0u};
  if (t < 1024) {
    const int s = t >> 8, o = t & 255;
    xn2p[(long)s * 131328 + o] = z;
  } else {
    t -= 1024;
    if (t < 32768) {
      const int s = t >> 13, o = t & 8191;
      f1p[(long)s * 532480 + o] = z;
    }
  }
}

// ---------------- transpose+cast+scale (f32 [K][N] -> bf16 [N][K]) ----------------
__global__ __launch_bounds__(256) void ktranspose(const float* __restrict__ in, u16* __restrict__ out,
                                                  int K, int N, float scale) {
  __shared__ u16 t[32][33];
  const int k0 = blockIdx.x * 32, n0 = blockIdx.y * 32;
  const int tx = threadIdx.x, ty = threadIdx.y;
#pragma unroll
  for (int i = ty; i < 32; i += 8) t[i][tx] = f2bf(in[(long)(k0 + i) * N + (n0 + tx)] * scale);
  __syncthreads();
#pragma unroll
  for (int i = ty; i < 32; i += 8) out[(long)(n0 + i) * K + (k0 + tx)] = t[tx][i];
}

// ---------------- layernorm (ddof=1, eps added to std) ----------------
template <int OUTBF>
__global__ __launch_bounds__(256) void ln_kernel(const float* __restrict__ inv, void* __restrict__ outv,
                                                 const float* __restrict__ g, const float* __restrict__ bsh,
                                                 int OSEGR, int OGUARD) {
  const int tid = threadIdx.x;
  const int lane = tid & 63;
  const long row = (long)blockIdx.x * 4 + (tid >> 6);
  const int c0 = lane * 4;
  float v[4];
  float4 f = *(const float4*)(inv + row * HDIM + c0);
  v[0] = f.x; v[1] = f.y; v[2] = f.z; v[3] = f.w;
  float s = v[0] + v[1] + v[2] + v[3];
#pragma unroll
  for (int o = 32; o > 0; o >>= 1) s += __shfl_xor(s, o);
  const float mean = s * (1.0f / 256.0f);
  float ss = 0.f;
#pragma unroll
  for (int j = 0; j < 4; ++j) { float d = v[j] - mean; ss += d * d; }
#pragma unroll
  for (int o = 32; o > 0; o >>= 1) ss += __shfl_xor(ss, o);
  const float inv_ = 1.0f / (sqrtf(ss * (1.0f / 255.0f)) + 1e-9f);
  float y[4];
#pragma unroll
  for (int j = 0; j < 4; ++j) y[j] = g[c0 + j] * (v[j] - mean) * inv_ + bsh[c0 + j];
  if (OUTBF) {
    const long orow = (row >> 12) * OSEGR + OGUARD + (row & (S_LEN - 1));
    uint2 o_;
    o_.x = (u32)f2bf(y[0]) | ((u32)f2bf(y[1]) << 16);
    o_.y = (u32)f2bf(y[2]) | ((u32)f2bf(y[3]) << 16);
    *(uint2*)((u16*)outv + orow * HDIM + c0) = o_;
  } else {
    float4 o_; o_.x = y[0]; o_.y = y[1]; o_.z = y[2]; o_.w = y[3];
    *(float4*)((float*)outv + row * HDIM + c0) = o_;
  }
}

// ------- depthwise 9-tap + gelu, then fused pw transforms -> gq,gk,gv (bf16) -------
__global__ __launch_bounds__(256) void dwconv_qkv(const float* __restrict__ xn,
                                                  u16* __restrict__ gq, u16* __restrict__ gk, u16* __restrict__ gv,
                                                  const float* __restrict__ dw_w, const float* __restrict__ dw_b,
                                                  const float* __restrict__ pw_w, const float* __restrict__ pw_b) {
  const int tid = threadIdx.x;
  const int lane = tid & 63;
  const long row = (long)blockIdx.x * 4 + (tid >> 6);
  const int sl = (int)(row & (S_LEN - 1));
  const float b0 = dw_b[0];
  float a0 = b0, a1 = b0, a2 = b0, a3 = b0;
#pragma unroll
  for (int t = 0; t < 9; ++t) {
    const int s2 = sl + t - 4;
    if (s2 >= 0 && s2 < S_LEN) {
      const float w = dw_w[t];
      float4 xv = *(const float4*)(xn + (row + t - 4) * HDIM + lane * 4);
      a0 = fmaf(w, xv.x, a0); a1 = fmaf(w, xv.y, a1);
      a2 = fmaf(w, xv.z, a2); a3 = fmaf(w, xv.w, a3);
    }
  }
  float h[4];
  h[0] = gelu_f(a0); h[1] = gelu_f(a1); h[2] = gelu_f(a2); h[3] = gelu_f(a3);
  u16* outs[3] = {gq, gk, gv};
#pragma unroll
  for (int p = 0; p < 3; ++p) {
    const float pw = pw_w[p], pb = pw_b[p];
    float y[4];
#pragma unroll
    for (int j = 0; j < 4; ++j) y[j] = gelu_f(fmaf(h[j], pw, pb));
    uint2 o_;
    o_.x = (u32)f2bf(y[0]) | ((u32)f2bf(y[1]) << 16);
    o_.y = (u32)f2bf(y[2]) | ((u32)f2bf(y[3]) << 16);
    *(uint2*)(outs[p] + row * HDIM + lane * 4) = o_;
  }
}

// ---------------- plain MFMA GEMM (QKV via grid.z / Wo+residual) ----------------
// EPI 0: z=0,1 -> bf16 out at Outv + z*o_z; z=2 -> bf16 transposed [b][h][d][s] into vt
// EPI 1: f32 out + f32 residual
template <int EPI>
__global__ __launch_bounds__(256) void gemm_glds(
    const u16* __restrict__ A, const u16* __restrict__ BT, void* __restrict__ Outv,
    u16* __restrict__ vt, const float* __restrict__ residv, int KW, int N,
    long a_z, long b_z, long o_z) {
  __shared__ __align__(16) u16 As[128 * 64];
  __shared__ __align__(16) u16 Bs[128 * 64];
  const int tid = threadIdx.x;
  const int lane = tid & 63;
  const int wid = tid >> 6;
  const int wm = (wid & 1) * 64;
  const int wn = (wid >> 1) * 64;
  const int fm = lane & 15;
  const int fq = lane >> 4;
  const int t0 = blockIdx.x * 128;
  const int n0 = blockIdx.y * 128;
  A += (long)blockIdx.z * a_z;
  BT += (long)blockIdx.z * b_z;

  const int srow = lane >> 3;
  const int cseg = (((lane & 7) ^ srow) << 3);

  f32x4 acc[4][4];
#pragma unroll
  for (int a = 0; a < 4; ++a)
#pragma unroll
    for (int b = 0; b < 4; ++b) acc[a][b] = (f32x4){0.f, 0.f, 0.f, 0.f};

  u16* alb = &As[wid * 32 * 64];
  u16* blb = &Bs[wid * 32 * 64];

  for (int k0 = 0; k0 < KW; k0 += 64) {
    const u16* ag = A + (long)(t0 + wid * 32 + srow) * KW + k0 + cseg;
    const u16* bg = BT + (long)(n0 + wid * 32 + srow) * KW + k0 + cseg;
#pragma unroll
    for (int j = 0; j < 4; ++j) {
      glds16(ag + (long)(8 * j) * KW, alb + j * 8 * 64);
      glds16(bg + (long)(8 * j) * KW, blb + j * 8 * 64);
    }
    __syncthreads();
#pragma unroll
    for (int kk = 0; kk < 2; ++kk) {
      const int g = kk * 4 + fq;
      bf16x8 af[4], bfv[4];
#pragma unroll
      for (int t = 0; t < 4; ++t) {
        const int ra = wm + t * 16 + fm;
        af[t] = *(const bf16x8*)&As[ra * 64 + ((g ^ (ra & 7)) << 3)];
        const int rb = wn + t * 16 + fm;
        bfv[t] = *(const bf16x8*)&Bs[rb * 64 + ((g ^ (rb & 7)) << 3)];
      }
#pragma unroll
      for (int mi = 0; mi < 4; ++mi)
#pragma unroll
        for (int ni = 0; ni < 4; ++ni)
          acc[mi][ni] = __builtin_amdgcn_mfma_f32_16x16x32_bf16(af[mi], bfv[ni], acc[mi][ni], 0, 0, 0);
    }
    __syncthreads();
  }

#pragma unroll
  for (int mi = 0; mi < 4; ++mi)
#pragma unroll
    for (int ni = 0; ni < 4; ++ni) {
      if (EPI == 0 && blockIdx.z == 2) {
        const int col = n0 + wn + ni * 16 + fm;
        const int hh = col >> 5, dd = col & 31;
        const long trow0 = t0 + wm + mi * 16 + fq * 4;
        const long bb = trow0 >> 12;
        const int s0 = (int)(trow0 & (S_LEN - 1));
        uint2 o_;
        o_.x = (u32)f2bf(acc[mi][ni][0]) | ((u32)f2bf(acc[mi][ni][1]) << 16);
        o_.y = (u32)f2bf(acc[mi][ni][2]) | ((u32)f2bf(acc[mi][ni][3]) << 16);
        *(uint2*)(vt + ((bb * 8 + hh) * 32 + dd) * S_LEN + s0) = o_;
      } else {
#pragma unroll
        for (int r = 0; r < 4; ++r) {
          const long trow = t0 + wm + mi * 16 + fq * 4 + r;
          const int col = n0 + wn + ni * 16 + fm;
          const float cv = acc[mi][ni][r];
          if (EPI == 0) {
            ((u16*)Outv + (long)blockIdx.z * o_z)[trow * N + col] = f2bf(cv);
          } else {
            ((float*)Outv)[trow * N + col] = cv + residv[trow * N + col];
          }
        }
      }
    }
}

// ---------------- MFMA flash attention (unchanged from R6) ----------------
__global__ __launch_bounds__(256) void attn_mfma(const u16* __restrict__ Q, const u16* __restrict__ K,
                                                 const u16* __restrict__ VT, const float* __restrict__ rel,
                                                 u16* __restrict__ CTX) {
  __shared__ __align__(16) u16 Ks[384 * 36];
  __shared__ __align__(16) u16 VTs[32 * 388];
  __shared__ __align__(16) u16 Ps[4][32 * 72];
  __shared__ float bias_s[260];
  const int c = blockIdx.x, h = blockIdx.y, b = blockIdx.z;
  const int tid = threadIdx.x;
  const int lane = tid & 63, wid = tid >> 6;
  const int fm = lane & 15, fq = lane >> 4;
  const int j0 = c * 128 - 128;
  const long kvbase = ((long)b * S_LEN) * HDIM + h * 32;
  const long vtbase = (((long)b * 8 + h) * 32) * S_LEN;

  for (int idx = tid; idx < 384 * 4; idx += 256) {
    const int jj = idx >> 2, seg = (idx & 3) * 8;
    int j = j0 + jj; j = j < 0 ? 0 : (j > S_LEN - 1 ? S_LEN - 1 : j);
    uint4 kv = *(const uint4*)(K + kvbase + (long)j * HDIM + seg);
    *(uint4*)&Ks[jj * 36 + seg] = kv;
  }
#pragma unroll
  for (int p = 0; p < 6; ++p) {
    const int idx = p * 256 + tid;
    const int d = idx / 48, seg = idx - d * 48;
    int off = j0 + seg * 8; off = off < 0 ? 0 : (off > S_LEN - 8 ? S_LEN - 8 : off);
    uint4 vv = *(const uint4*)(VT + vtbase + (long)d * S_LEN + off);
    *(uint4*)&VTs[d * 388 + seg * 8] = vv;
  }
  for (int idx = tid; idx < 257; idx += 256) bias_s[idx] = rel[idx];
  __syncthreads();

  bf16x8 aq[2];
#pragma unroll
  for (int mi = 0; mi < 2; ++mi)
    aq[mi] = *(const bf16x8*)(Q + kvbase + (long)(c * 128 + wid * 32 + mi * 16 + fm) * HDIM + fq * 8);

  const int klo = (c == 0) ? 128 : 0;
  const int khi = (c == 31) ? 255 : 383;

  float m_r[2][4], l_r[2][4];
  f32x4 acc[2][2];
#pragma unroll
  for (int mi = 0; mi < 2; ++mi)
#pragma unroll
    for (int r = 0; r < 4; ++r) { m_r[mi][r] = -1e9f; l_r[mi][r] = 0.f; }
#pragma unroll
  for (int mi = 0; mi < 2; ++mi)
#pragma unroll
    for (int nd = 0; nd < 2; ++nd) acc[mi][nd] = (f32x4){0.f, 0.f, 0.f, 0.f};

  u16* pw = &Ps[wid][0];

  for (int ch = 0; ch < 6; ++ch) {
    f32x4 sc[2][4];
#pragma unroll
    for (int ni = 0; ni < 4; ++ni) {
      bf16x8 bk = *(const bf16x8*)&Ks[(ch * 64 + ni * 16 + fm) * 36 + fq * 8];
#pragma unroll
      for (int mi = 0; mi < 2; ++mi)
        sc[mi][ni] = __builtin_amdgcn_mfma_f32_16x16x32_bf16(aq[mi], bk, (f32x4){0.f, 0.f, 0.f, 0.f}, 0, 0, 0);
    }
    float cm[2][4];
#pragma unroll
    for (int mi = 0; mi < 2; ++mi)
#pragma unroll
      for (int r = 0; r < 4; ++r) cm[mi][r] = -1e9f;
#pragma unroll
    for (int mi = 0; mi < 2; ++mi)
#pragma unroll
      for (int ni = 0; ni < 4; ++ni) {
        const int keyloc = ch * 64 + ni * 16 + fm;
        const bool kval = (keyloc >= klo) && (keyloc <= khi);
#pragma unroll
        for (int r = 0; r < 4; ++r) {
          const int qloc = wid * 32 + mi * 16 + fq * 4 + r;
          const int rr = keyloc - qloc;
          const bool valid = kval && (rr >= 0) && (rr <= 256);
          const int rc = valid ? rr : 0;
          float vv = sc[mi][ni][r] + bias_s[rc];
          vv = valid ? vv : -1e9f;
          sc[mi][ni][r] = vv;
          cm[mi][r] = fmaxf(cm[mi][r], vv);
        }
      }
#pragma unroll
    for (int mi = 0; mi < 2; ++mi)
#pragma unroll
      for (int r = 0; r < 4; ++r) {
        float x = cm[mi][r];
        x = fmaxf(x, __shfl_xor(x, 1));
        x = fmaxf(x, __shfl_xor(x, 2));
        x = fmaxf(x, __shfl_xor(x, 4));
        x = fmaxf(x, __shfl_xor(x, 8));
        cm[mi][r] = x;
      }
    float alpha[2][4];
#pragma unroll
    for (int mi = 0; mi < 2; ++mi)
#pragma unroll
      for (int r = 0; r < 4; ++r) {
        const float nm = fmaxf(m_r[mi][r], cm[mi][r]);
        alpha[mi][r] = __expf(m_r[mi][r] - nm);
        m_r[mi][r] = nm;
        l_r[mi][r] *= alpha[mi][r];
      }
#pragma unroll
    for (int mi = 0; mi < 2; ++mi)
#pragma unroll
      for (int nd = 0; nd < 2; ++nd)
#pragma unroll
        for (int r = 0; r < 4; ++r) acc[mi][nd][r] *= alpha[mi][r];
#pragma unroll
    for (int mi = 0; mi < 2; ++mi)
#pragma unroll
      for (int ni = 0; ni < 4; ++ni)
#pragma unroll
        for (int r = 0; r < 4; ++r) {
          const float pv = __expf(sc[mi][ni][r] - m_r[mi][r]);
          l_r[mi][r] += pv;
          pw[(mi * 16 + fq * 4 + r) * 72 + ni * 16 + fm] = f2bf(pv);
        }
#pragma unroll
    for (int kc = 0; kc < 2; ++kc) {
      bf16x8 ap[2], bv[2];
#pragma unroll
      for (int mi = 0; mi < 2; ++mi)
        ap[mi] = *(const bf16x8*)&pw[(mi * 16 + fm) * 72 + kc * 32 + fq * 8];
#pragma unroll
      for (int nd = 0; nd < 2; ++nd)
        bv[nd] = *(const bf16x8*)&VTs[(nd * 16 + fm) * 388 + ch * 64 + kc * 32 + fq * 8];
#pragma unroll
      for (int mi = 0; mi < 2; ++mi)
#pragma unroll
        for (int nd = 0; nd < 2; ++nd)
          acc[mi][nd] = __builtin_amdgcn_mfma_f32_16x16x32_bf16(ap[mi], bv[nd], acc[mi][nd], 0, 0, 0);
    }
  }

  float linv[2][4];
#pragma unroll
  for (int mi = 0; mi < 2; ++mi)
#pragma unroll
    for (int r = 0; r < 4; ++r) {
      float x = l_r[mi][r];
      x += __shfl_xor(x, 1);
      x += __shfl_xor(x, 2);
      x += __shfl_xor(x, 4);
      x += __shfl_xor(x, 8);
      linv[mi][r] = 1.0f / x;
    }
#pragma unroll
  for (int mi = 0; mi < 2; ++mi)
#pragma unroll
    for (int nd = 0; nd < 2; ++nd)
#pragma unroll
      for (int r = 0; r < 4; ++r) {
        const long s = c * 128 + wid * 32 + mi * 16 + fq * 4 + r;
        CTX[((long)b * S_LEN + s) * HDIM + h * 32 + nd * 16 + fm] = f2bf(acc[mi][nd][r] * linv[mi][r]);
      }
}

// ---------------- conv MFMA GEMM: 256x128 block, wave 128x64 (8x4 acc) ----------------
// All 9 taps per block; split-K over k0-range via blockIdx.z (ZSPLIT).
// EPI 2: bf16 gelu(acc+bias) into padded out; EPI 3: f32 partial at +z*out_z_off
template <int EPI, int APITCH, int NTAPS, int DIL, int NN, int ZSPLIT>
__global__ __launch_bounds__(256, 2) void gemm_conv(
    const u16* __restrict__ Apad, const u16* __restrict__ BT, void* __restrict__ Outv,
    const float* __restrict__ bias,
    int SEGR, int BPITCH, int OSEGR, int OGUARD, long out_z_off) {
  constexpr int AROWS = 256 + (NTAPS - 1) * DIL;
  constexpr int AOPS = (AROWS + 7) / 8;
  constexpr int KITERS = APITCH / 64;
  __shared__ __align__(16) u16 As[AOPS * 8 * 64];
  __shared__ __align__(16) u16 Bs2[2][128 * 64];
  const int tid = threadIdx.x;
  const int lane = tid & 63;
  const int wid = tid >> 6;
  const int wm = (wid & 1) * 128;
  const int wn = (wid >> 1) * 64;
  const int fm = lane & 15;
  const int fq = lane >> 4;
  const int t0 = blockIdx.x * 256;
  const int n0 = blockIdx.y * 128;
  const int zz = blockIdx.z;
  const int k_lo = ((zz * KITERS) / ZSPLIT) * 64;
  const int k_hi = (((zz + 1) * KITERS) / ZSPLIT) * 64;

  const int seg = t0 >> 12;
  const long abase = (long)seg * SEGR + (t0 & (S_LEN - 1));
  const int srow = lane >> 3;
  const int cseg = (((lane & 7) ^ srow) << 3);

  f32x4 acc[8][4];
#pragma unroll
  for (int a = 0; a < 8; ++a)
#pragma unroll
    for (int b = 0; b < 4; ++b) acc[a][b] = (f32x4){0.f, 0.f, 0.f, 0.f};

  for (int k0 = k_lo; k0 < k_hi; k0 += 64) {
    for (int op = wid; op < AOPS; op += 4)
      glds16(Apad + (abase + op * 8 + srow) * APITCH + k0 + cseg, &As[op * 8 * 64]);
#pragma unroll
    for (int j = 0; j < 4; ++j)
      glds16(BT + (long)(n0 + wid * 32 + j * 8 + srow) * BPITCH + k0 + cseg,
             &Bs2[0][(wid * 32 + j * 8) * 64]);
    __syncthreads();
#pragma unroll
    for (int u = 0; u < NTAPS; ++u) {
      if (u + 1 < NTAPS) {
        const long bc = (long)(u + 1) * APITCH + k0;
#pragma unroll
        for (int j = 0; j < 4; ++j)
          glds16(BT + (long)(n0 + wid * 32 + j * 8 + srow) * BPITCH + bc + cseg,
                 &Bs2[(u + 1) & 1][(wid * 32 + j * 8) * 64]);
      }
      const int du = u * DIL;
      const u16* bsp = Bs2[u & 1];
#pragma unroll
      for (int kk = 0; kk < 2; ++kk) {
        const int g = kk * 4 + fq;
        bf16x8 af[8], bfv[4];
#pragma unroll
        for (int t = 0; t < 8; ++t) {
          const int ra = wm + t * 16 + fm + du;
          af[t] = *(const bf16x8*)&As[ra * 64 + ((g ^ (ra & 7)) << 3)];
        }
#pragma unroll
        for (int t = 0; t < 4; ++t) {
          const int rb = wn + t * 16 + fm;
          bfv[t] = *(const bf16x8*)&bsp[rb * 64 + ((g ^ (rb & 7)) << 3)];
        }
#pragma unroll
        for (int mi = 0; mi < 8; ++mi)
#pragma unroll
          for (int ni = 0; ni < 4; ++ni)
            acc[mi][ni] = __builtin_amdgcn_mfma_f32_16x16x32_bf16(af[mi], bfv[ni], acc[mi][ni], 0, 0, 0);
      }
      __syncthreads();
    }
  }

#pragma unroll
  for (int mi = 0; mi < 8; ++mi)
#pragma unroll
    for (int ni = 0; ni < 4; ++ni)
#pragma unroll
      for (int r = 0; r < 4; ++r) {
        const long trow = t0 + wm + mi * 16 + fq * 4 + r;
        const int col = n0 + wn + ni * 16 + fm;
        const float cv = acc[mi][ni][r];
        if (EPI == 2) {
          const long orow = (trow >> 12) * OSEGR + OGUARD + (trow & (S_LEN - 1));
          ((u16*)Outv)[orow * NN + col] = f2bf(gelu_f(cv + bias[col]));
        } else {
          (((float*)Outv) + (long)zz * out_z_off)[trow * NN + col] = cv;
        }
      }
}

// ---------------- final: out = x2 + gelu(P0+P1+P2 + b2)  (f32 out) ----------------
__global__ __launch_bounds__(256) void final_kernel(const float* __restrict__ x2, const float* __restrict__ P,
                                                    const float* __restrict__ b2, float* __restrict__ out) {
  const long i4 = ((long)blockIdx.x * 256 + threadIdx.x) * 4;
  const int c0 = (int)(i4 & (HDIM - 1));
  float4 xa = *(const float4*)(x2 + i4);
  float4 p0 = *(const float4*)(P + i4);
  float4 p1 = *(const float4*)(P + 4194304 + i4);
  float4 p2 = *(const float4*)(P + 8388608 + i4);
  const float pv[4] = {p0.x + p1.x + p2.x, p0.y + p1.y + p2.y, p0.z + p1.z + p2.z, p0.w + p1.w + p2.w};
  float4 o_;
  o_.x = xa.x + gelu_f(pv[0] + b2[c0 + 0]);
  o_.y = xa.y + gelu_f(pv[1] + b2[c0 + 1]);
  o_.z = xa.z + gelu_f(pv[2] + b2[c0 + 2]);
  o_.w = xa.w + gelu_f(pv[3] + b2[c0 + 3]);
  *(float4*)(out + i4) = o_;
}

extern "C" void kernel_launch(void* const* d_in, const int* in_sizes, int n_in,
                              void* d_out, int out_size, void* d_ws, size_t ws_size,
                              hipStream_t stream) {
  (void)in_sizes; (void)n_in; (void)out_size;
  const float* X    = (const float*)d_in[0];
  const float* dw_w = (const float*)d_in[1];
  const float* dw_b = (const float*)d_in[2];
  const float* pw_w = (const float*)d_in[3];
  const float* pw_b = (const float*)d_in[4];
  const float* Wq   = (const float*)d_in[5];
  const float* Wk   = (const float*)d_in[6];
  const float* Wv   = (const float*)d_in[7];
  const float* Wo   = (const float*)d_in[8];
  const float* rel  = (const float*)d_in[9];
  const float* ln1g = (const float*)d_in[10];
  const float* ln1b = (const float*)d_in[11];
  const float* ln2g = (const float*)d_in[12];
  const float* ln2b = (const float*)d_in[13];
  const float* w1   = (const float*)d_in[14];
  const float* b1   = (const float*)d_in[15];
  const float* w2   = (const float*)d_in[16];
  const float* b2   = (const float*)d_in[17];

  if (ws_size < 119537664) return;

  char* ws = (char*)d_ws;
  u16* WqT = (u16*)(ws + 0);
  u16* WkT = (u16*)(ws + 131072);
  u16* WvT = (u16*)(ws + 262144);
  u16* WoT = (u16*)(ws + 393216);
  u16* W1T = (u16*)(ws + 524288);
  u16* W2T = (u16*)(ws + 5242880);
  float* xn  = (float*)(ws + 10485760);   // 16 MiB, reused as x2
  float* x2  = xn;
  u16* gq  = (u16*)(ws + 27262976);
  u16* gk  = (u16*)(ws + 35651584);
  u16* gv  = (u16*)(ws + 44040192);
  u16* q   = (u16*)(ws + 52428800);       // q,k contiguous (o_z = 4M elems)
  u16* vt  = (u16*)(ws + 69206016);       // V^T [b][h][32][4096]
  u16* ctx = (u16*)(ws + 77594624);
  // phase-2 overlays (valid only after attn + Wo done)
  u16* f1p  = (u16*)(ws + 27262976);
  u16* xn2p = (u16*)(ws + 61341696);
  float* P  = (float*)(ws + 61341696);

  const float qscale = 0.17677669529663687f;
  dim3 tb(32, 8);
  ktranspose<<<dim3(8, 8), tb, 0, stream>>>(Wq, WqT, 256, 256, qscale);
  ktranspose<<<dim3(8, 8), tb, 0, stream>>>(Wk, WkT, 256, 256, 1.0f);
  ktranspose<<<dim3(8, 8), tb, 0, stream>>>(Wv, WvT, 256, 256, 1.0f);
  ktranspose<<<dim3(8, 8), tb, 0, stream>>>(Wo, WoT, 256, 256, 1.0f);
  ktranspose<<<dim3(72, 32), tb, 0, stream>>>(w1, W1T, 2304, 1024, 1.0f);
  ktranspose<<<dim3(288, 8), tb, 0, stream>>>(w2, W2T, 9216, 256, 1.0f);

  ln_kernel<0><<<4096, 256, 0, stream>>>(X, xn, ln1g, ln1b, 4096, 0);
  dwconv_qkv<<<4096, 256, 0, stream>>>(xn, gq, gk, gv, dw_w, dw_b, pw_w, pw_b);

  gemm_glds<0><<<dim3(128, 2, 3), 256, 0, stream>>>(gq, WqT, q, vt, nullptr,
      256, 256, 4194304, 65536, 4194304);

  attn_mfma<<<dim3(32, 8, 4), 256, 0, stream>>>(q, q + 4194304, vt, rel, ctx);

  gemm_glds<1><<<dim3(128, 2), 256, 0, stream>>>(ctx, WoT, x2, nullptr, X, 256, 256, 0, 0, 0);

  zero_guards<<<132, 256, 0, stream>>>((uint4*)xn2p, (uint4*)f1p);

  ln_kernel<1><<<4096, 256, 0, stream>>>(x2, xn2p, ln2g, ln2b, 4104, 8);

  // conv1: 256x128 tiles, 9 taps dil 1, K=256 (no k-split)
  gemm_conv<2, 256, 9, 1, 1024, 1><<<dim3(64, 8, 1), 256, 0, stream>>>(
      xn2p, W1T, f1p, b1, 4104, 2304, 4160, 64, 0);

  // conv2: 256x128 tiles, 9 taps dil 8, K=1024 split over 3 k0-ranges -> fp32 partials
  gemm_conv<3, 1024, 9, 8, 256, 3><<<dim3(64, 2, 3), 256, 0, stream>>>(
      f1p, W2T, P, nullptr, 4160, 9216, 0, 0, 4194304);

  final_kernel<<<4096, 256, 0, stream>>>(x2, P, b2, (float*)d_out);
}

// Round 8
// 389.213 us; speedup vs baseline: 1.0504x; 1.0504x over previous
//
#include <hip/hip_runtime.h>
#include <stdint.h>

typedef uint16_t u16;
typedef uint32_t u32;

typedef __attribute__((ext_vector_type(8))) short bf16x8;
typedef __attribute__((ext_vector_type(4))) float f32x4;

typedef __attribute__((address_space(1))) const u32 gas_u32;
typedef __attribute__((address_space(3))) u32 las_u32;

#define S_LEN 4096
#define HDIM  256
#define FFDIM 1024

__device__ __forceinline__ float bf2f(u16 u) { return __uint_as_float(((u32)u) << 16); }
__device__ __forceinline__ u16 f2bf(float f) {
  u32 x = __float_as_uint(f);
  return (u16)((x + 0x7fffu + ((x >> 16) & 1u)) >> 16);
}
__device__ __forceinline__ float gelu_f(float x) {
  return 0.5f * x * (1.0f + erff(x * 0.7071067811865475f));
}
__device__ __forceinline__ void glds16(const u16* g, u16* l) {
  __builtin_amdgcn_global_load_lds((gas_u32*)g, (las_u32*)l, 16, 0, 0);
}

// ---------------- fused transpose+cast of all 6 weight matrices ----------------
// regions (32x32 tiles): Wq[0,64) Wk[64,128) Wv[128,192) Wo[192,256) W1[256,2560) W2[2560,4864)
__global__ __launch_bounds__(256) void ktranspose_all(
    const float* __restrict__ Wq, const float* __restrict__ Wk, const float* __restrict__ Wv,
    const float* __restrict__ Wo, const float* __restrict__ W1, const float* __restrict__ W2,
    u16* __restrict__ WqT, u16* __restrict__ WkT, u16* __restrict__ WvT,
    u16* __restrict__ WoT, u16* __restrict__ W1T, u16* __restrict__ W2T, float qscale) {
  __shared__ u16 t[32][33];
  const int bid = blockIdx.x;
  const float* in; u16* out; int K, N; float scale = 1.0f; int idx;
  if (bid < 256) {
    K = 256; N = 256; idx = bid & 63;
    const int w = bid >> 6;
    in = (w == 0) ? Wq : (w == 1) ? Wk : (w == 2) ? Wv : Wo;
    out = (w == 0) ? WqT : (w == 1) ? WkT : (w == 2) ? WvT : WoT;
    if (w == 0) scale = qscale;
  } else if (bid < 2560) {
    K = 2304; N = 1024; idx = bid - 256; in = W1; out = W1T;
  } else {
    K = 9216; N = 256; idx = bid - 2560; in = W2; out = W2T;
  }
  const int kt = K >> 5;
  const int k0 = (idx % kt) * 32, n0 = (idx / kt) * 32;
  const int tx = threadIdx.x, ty = threadIdx.y;
#pragma unroll
  for (int i = ty; i < 32; i += 8) t[i][tx] = f2bf(in[(long)(k0 + i) * N + (n0 + tx)] * scale);
  __syncthreads();
#pragma unroll
  for (int i = ty; i < 32; i += 8) out[(long)(n0 + i) * K + (k0 + tx)] = t[tx][i];
}

// ---------------- layernorm (ddof=1, eps added to std) ----------------
// OUTBF=1 also zeroes guard rows via extra blocks (grid 4096+132)
template <int OUTBF>
__global__ __launch_bounds__(256) void ln_kernel(const float* __restrict__ inv, void* __restrict__ outv,
                                                 const float* __restrict__ g, const float* __restrict__ bsh,
                                                 int OSEGR, int OGUARD,
                                                 uint4* __restrict__ gx, uint4* __restrict__ gf) {
  const int tid = threadIdx.x;
  if (OUTBF && blockIdx.x >= 4096) {
    int t = (blockIdx.x - 4096) * 256 + tid;
    const uint4 z = {0u, 0u, 0u, 0u};
    if (t < 1024) {
      const int s = t >> 8, o = t & 255;
      gx[(long)s * 131328 + o] = z;
    } else {
      t -= 1024;
      if (t < 32768) {
        const int s = t >> 13, o = t & 8191;
        gf[(long)s * 532480 + o] = z;
      }
    }
    return;
  }
  const int lane = tid & 63;
  const long row = (long)blockIdx.x * 4 + (tid >> 6);
  const int c0 = lane * 4;
  float v[4];
  float4 f = *(const float4*)(inv + row * HDIM + c0);
  v[0] = f.x; v[1] = f.y; v[2] = f.z; v[3] = f.w;
  float s = v[0] + v[1] + v[2] + v[3];
#pragma unroll
  for (int o = 32; o > 0; o >>= 1) s += __shfl_xor(s, o);
  const float mean = s * (1.0f / 256.0f);
  float ss = 0.f;
#pragma unroll
  for (int j = 0; j < 4; ++j) { float d = v[j] - mean; ss += d * d; }
#pragma unroll
  for (int o = 32; o > 0; o >>= 1) ss += __shfl_xor(ss, o);
  const float inv_ = 1.0f / (sqrtf(ss * (1.0f / 255.0f)) + 1e-9f);
  float y[4];
#pragma unroll
  for (int j = 0; j < 4; ++j) y[j] = g[c0 + j] * (v[j] - mean) * inv_ + bsh[c0 + j];
  if (OUTBF) {
    const long orow = (row >> 12) * OSEGR + OGUARD + (row & (S_LEN - 1));
    uint2 o_;
    o_.x = (u32)f2bf(y[0]) | ((u32)f2bf(y[1]) << 16);
    o_.y = (u32)f2bf(y[2]) | ((u32)f2bf(y[3]) << 16);
    *(uint2*)((u16*)outv + orow * HDIM + c0) = o_;
  } else {
    float4 o_; o_.x = y[0]; o_.y = y[1]; o_.z = y[2]; o_.w = y[3];
    *(float4*)((float*)outv + row * HDIM + c0) = o_;
  }
}

// ------- depthwise 9-tap + gelu, then fused pw transforms -> gq,gk,gv (bf16) -------
__global__ __launch_bounds__(256) void dwconv_qkv(const float* __restrict__ xn,
                                                  u16* __restrict__ gq, u16* __restrict__ gk, u16* __restrict__ gv,
                                                  const float* __restrict__ dw_w, const float* __restrict__ dw_b,
                                                  const float* __restrict__ pw_w, const float* __restrict__ pw_b) {
  const int tid = threadIdx.x;
  const int lane = tid & 63;
  const long row = (long)blockIdx.x * 4 + (tid >> 6);
  const int sl = (int)(row & (S_LEN - 1));
  const float b0 = dw_b[0];
  float a0 = b0, a1 = b0, a2 = b0, a3 = b0;
#pragma unroll
  for (int t = 0; t < 9; ++t) {
    const int s2 = sl + t - 4;
    if (s2 >= 0 && s2 < S_LEN) {
      const float w = dw_w[t];
      float4 xv = *(const float4*)(xn + (row + t - 4) * HDIM + lane * 4);
      a0 = fmaf(w, xv.x, a0); a1 = fmaf(w, xv.y, a1);
      a2 = fmaf(w, xv.z, a2); a3 = fmaf(w, xv.w, a3);
    }
  }
  float h[4];
  h[0] = gelu_f(a0); h[1] = gelu_f(a1); h[2] = gelu_f(a2); h[3] = gelu_f(a3);
  u16* outs[3] = {gq, gk, gv};
#pragma unroll
  for (int p = 0; p < 3; ++p) {
    const float pw = pw_w[p], pb = pw_b[p];
    float y[4];
#pragma unroll
    for (int j = 0; j < 4; ++j) y[j] = gelu_f(fmaf(h[j], pw, pb));
    uint2 o_;
    o_.x = (u32)f2bf(y[0]) | ((u32)f2bf(y[1]) << 16);
    o_.y = (u32)f2bf(y[2]) | ((u32)f2bf(y[3]) << 16);
    *(uint2*)(outs[p] + row * HDIM + lane * 4) = o_;
  }
}

// ---------------- 256x128 MFMA GEMM (QKV, z selects A/B/out; z==2 -> vt transpose) ----------------
__global__ __launch_bounds__(256) void gemm_big(
    const u16* __restrict__ A, const u16* __restrict__ BT, void* __restrict__ Outv,
    u16* __restrict__ vt, int KW, int N, long a_z, long b_z, long o_z) {
  __shared__ __align__(16) u16 As[256 * 64];
  __shared__ __align__(16) u16 Bs[128 * 64];
  const int tid = threadIdx.x;
  const int lane = tid & 63;
  const int wid = tid >> 6;
  const int wm = (wid & 1) * 128;
  const int wn = (wid >> 1) * 64;
  const int fm = lane & 15;
  const int fq = lane >> 4;
  const int t0 = blockIdx.x * 256;
  const int n0 = blockIdx.y * 128;
  A += (long)blockIdx.z * a_z;
  BT += (long)blockIdx.z * b_z;

  const int srow = lane >> 3;
  const int cseg = (((lane & 7) ^ srow) << 3);

  f32x4 acc[8][4];
#pragma unroll
  for (int a = 0; a < 8; ++a)
#pragma unroll
    for (int b = 0; b < 4; ++b) acc[a][b] = (f32x4){0.f, 0.f, 0.f, 0.f};

  for (int k0 = 0; k0 < KW; k0 += 64) {
    for (int op = wid; op < 32; op += 4)
      glds16(A + (long)(t0 + op * 8 + srow) * KW + k0 + cseg, &As[op * 8 * 64]);
#pragma unroll
    for (int j = 0; j < 4; ++j)
      glds16(BT + (long)(n0 + wid * 32 + j * 8 + srow) * KW + k0 + cseg,
             &Bs[(wid * 32 + j * 8) * 64]);
    __syncthreads();
#pragma unroll
    for (int kk = 0; kk < 2; ++kk) {
      const int g = kk * 4 + fq;
      bf16x8 af[8], bfv[4];
#pragma unroll
      for (int t = 0; t < 8; ++t) {
        const int ra = wm + t * 16 + fm;
        af[t] = *(const bf16x8*)&As[ra * 64 + ((g ^ (ra & 7)) << 3)];
      }
#pragma unroll
      for (int t = 0; t < 4; ++t) {
        const int rb = wn + t * 16 + fm;
        bfv[t] = *(const bf16x8*)&Bs[rb * 64 + ((g ^ (rb & 7)) << 3)];
      }
#pragma unroll
      for (int mi = 0; mi < 8; ++mi)
#pragma unroll
        for (int ni = 0; ni < 4; ++ni)
          acc[mi][ni] = __builtin_amdgcn_mfma_f32_16x16x32_bf16(af[mi], bfv[ni], acc[mi][ni], 0, 0, 0);
    }
    __syncthreads();
  }

#pragma unroll
  for (int mi = 0; mi < 8; ++mi)
#pragma unroll
    for (int ni = 0; ni < 4; ++ni) {
      if (blockIdx.z == 2) {
        const int col = n0 + wn + ni * 16 + fm;
        const int hh = col >> 5, dd = col & 31;
        const long trow0 = t0 + wm + mi * 16 + fq * 4;
        const long bb = trow0 >> 12;
        const int s0 = (int)(trow0 & (S_LEN - 1));
        uint2 o_;
        o_.x = (u32)f2bf(acc[mi][ni][0]) | ((u32)f2bf(acc[mi][ni][1]) << 16);
        o_.y = (u32)f2bf(acc[mi][ni][2]) | ((u32)f2bf(acc[mi][ni][3]) << 16);
        *(uint2*)(vt + ((bb * 8 + hh) * 32 + dd) * S_LEN + s0) = o_;
      } else {
#pragma unroll
        for (int r = 0; r < 4; ++r) {
          const long trow = t0 + wm + mi * 16 + fq * 4 + r;
          const int col = n0 + wn + ni * 16 + fm;
          ((u16*)Outv + (long)blockIdx.z * o_z)[trow * N + col] = f2bf(acc[mi][ni][r]);
        }
      }
    }
}

// ---------------- 128-tile MFMA GEMM (Wo + residual) ----------------
__global__ __launch_bounds__(256) void gemm_wo(
    const u16* __restrict__ A, const u16* __restrict__ BT, float* __restrict__ Outv,
    const float* __restrict__ residv, int KW, int N) {
  __shared__ __align__(16) u16 As[128 * 64];
  __shared__ __align__(16) u16 Bs[128 * 64];
  const int tid = threadIdx.x;
  const int lane = tid & 63;
  const int wid = tid >> 6;
  const int wm = (wid & 1) * 64;
  const int wn = (wid >> 1) * 64;
  const int fm = lane & 15;
  const int fq = lane >> 4;
  const int t0 = blockIdx.x * 128;
  const int n0 = blockIdx.y * 128;

  const int srow = lane >> 3;
  const int cseg = (((lane & 7) ^ srow) << 3);

  f32x4 acc[4][4];
#pragma unroll
  for (int a = 0; a < 4; ++a)
#pragma unroll
    for (int b = 0; b < 4; ++b) acc[a][b] = (f32x4){0.f, 0.f, 0.f, 0.f};

  u16* alb = &As[wid * 32 * 64];
  u16* blb = &Bs[wid * 32 * 64];

  for (int k0 = 0; k0 < KW; k0 += 64) {
    const u16* ag = A + (long)(t0 + wid * 32 + srow) * KW + k0 + cseg;
    const u16* bg = BT + (long)(n0 + wid * 32 + srow) * KW + k0 + cseg;
#pragma unroll
    for (int j = 0; j < 4; ++j) {
      glds16(ag + (long)(8 * j) * KW, alb + j * 8 * 64);
      glds16(bg + (long)(8 * j) * KW, blb + j * 8 * 64);
    }
    __syncthreads();
#pragma unroll
    for (int kk = 0; kk < 2; ++kk) {
      const int g = kk * 4 + fq;
      bf16x8 af[4], bfv[4];
#pragma unroll
      for (int t = 0; t < 4; ++t) {
        const int ra = wm + t * 16 + fm;
        af[t] = *(const bf16x8*)&As[ra * 64 + ((g ^ (ra & 7)) << 3)];
        const int rb = wn + t * 16 + fm;
        bfv[t] = *(const bf16x8*)&Bs[rb * 64 + ((g ^ (rb & 7)) << 3)];
      }
#pragma unroll
      for (int mi = 0; mi < 4; ++mi)
#pragma unroll
        for (int ni = 0; ni < 4; ++ni)
          acc[mi][ni] = __builtin_amdgcn_mfma_f32_16x16x32_bf16(af[mi], bfv[ni], acc[mi][ni], 0, 0, 0);
    }
    __syncthreads();
  }

#pragma unroll
  for (int mi = 0; mi < 4; ++mi)
#pragma unroll
    for (int ni = 0; ni < 4; ++ni)
#pragma unroll
      for (int r = 0; r < 4; ++r) {
        const long trow = t0 + wm + mi * 16 + fq * 4 + r;
        const int col = n0 + wn + ni * 16 + fm;
        Outv[trow * N + col] = acc[mi][ni][r] + residv[trow * N + col];
      }
}

// ---------------- MFMA flash attention (unchanged) ----------------
__global__ __launch_bounds__(256) void attn_mfma(const u16* __restrict__ Q, const u16* __restrict__ K,
                                                 const u16* __restrict__ VT, const float* __restrict__ rel,
                                                 u16* __restrict__ CTX) {
  __shared__ __align__(16) u16 Ks[384 * 36];
  __shared__ __align__(16) u16 VTs[32 * 388];
  __shared__ __align__(16) u16 Ps[4][32 * 72];
  __shared__ float bias_s[260];
  const int c = blockIdx.x, h = blockIdx.y, b = blockIdx.z;
  const int tid = threadIdx.x;
  const int lane = tid & 63, wid = tid >> 6;
  const int fm = lane & 15, fq = lane >> 4;
  const int j0 = c * 128 - 128;
  const long kvbase = ((long)b * S_LEN) * HDIM + h * 32;
  const long vtbase = (((long)b * 8 + h) * 32) * S_LEN;

  for (int idx = tid; idx < 384 * 4; idx += 256) {
    const int jj = idx >> 2, seg = (idx & 3) * 8;
    int j = j0 + jj; j = j < 0 ? 0 : (j > S_LEN - 1 ? S_LEN - 1 : j);
    uint4 kv = *(const uint4*)(K + kvbase + (long)j * HDIM + seg);
    *(uint4*)&Ks[jj * 36 + seg] = kv;
  }
#pragma unroll
  for (int p = 0; p < 6; ++p) {
    const int idx = p * 256 + tid;
    const int d = idx / 48, seg = idx - d * 48;
    int off = j0 + seg * 8; off = off < 0 ? 0 : (off > S_LEN - 8 ? S_LEN - 8 : off);
    uint4 vv = *(const uint4*)(VT + vtbase + (long)d * S_LEN + off);
    *(uint4*)&VTs[d * 388 + seg * 8] = vv;
  }
  for (int idx = tid; idx < 257; idx += 256) bias_s[idx] = rel[idx];
  __syncthreads();

  bf16x8 aq[2];
#pragma unroll
  for (int mi = 0; mi < 2; ++mi)
    aq[mi] = *(const bf16x8*)(Q + kvbase + (long)(c * 128 + wid * 32 + mi * 16 + fm) * HDIM + fq * 8);

  const int klo = (c == 0) ? 128 : 0;
  const int khi = (c == 31) ? 255 : 383;

  float m_r[2][4], l_r[2][4];
  f32x4 acc[2][2];
#pragma unroll
  for (int mi = 0; mi < 2; ++mi)
#pragma unroll
    for (int r = 0; r < 4; ++r) { m_r[mi][r] = -1e9f; l_r[mi][r] = 0.f; }
#pragma unroll
  for (int mi = 0; mi < 2; ++mi)
#pragma unroll
    for (int nd = 0; nd < 2; ++nd) acc[mi][nd] = (f32x4){0.f, 0.f, 0.f, 0.f};

  u16* pw = &Ps[wid][0];

  for (int ch = 0; ch < 6; ++ch) {
    f32x4 sc[2][4];
#pragma unroll
    for (int ni = 0; ni < 4; ++ni) {
      bf16x8 bk = *(const bf16x8*)&Ks[(ch * 64 + ni * 16 + fm) * 36 + fq * 8];
#pragma unroll
      for (int mi = 0; mi < 2; ++mi)
        sc[mi][ni] = __builtin_amdgcn_mfma_f32_16x16x32_bf16(aq[mi], bk, (f32x4){0.f, 0.f, 0.f, 0.f}, 0, 0, 0);
    }
    float cm[2][4];
#pragma unroll
    for (int mi = 0; mi < 2; ++mi)
#pragma unroll
      for (int r = 0; r < 4; ++r) cm[mi][r] = -1e9f;
#pragma unroll
    for (int mi = 0; mi < 2; ++mi)
#pragma unroll
      for (int ni = 0; ni < 4; ++ni) {
        const int keyloc = ch * 64 + ni * 16 + fm;
        const bool kval = (keyloc >= klo) && (keyloc <= khi);
#pragma unroll
        for (int r = 0; r < 4; ++r) {
          const int qloc = wid * 32 + mi * 16 + fq * 4 + r;
          const int rr = keyloc - qloc;
          const bool valid = kval && (rr >= 0) && (rr <= 256);
          const int rc = valid ? rr : 0;
          float vv = sc[mi][ni][r] + bias_s[rc];
          vv = valid ? vv : -1e9f;
          sc[mi][ni][r] = vv;
          cm[mi][r] = fmaxf(cm[mi][r], vv);
        }
      }
#pragma unroll
    for (int mi = 0; mi < 2; ++mi)
#pragma unroll
      for (int r = 0; r < 4; ++r) {
        float x = cm[mi][r];
        x = fmaxf(x, __shfl_xor(x, 1));
        x = fmaxf(x, __shfl_xor(x, 2));
        x = fmaxf(x, __shfl_xor(x, 4));
        x = fmaxf(x, __shfl_xor(x, 8));
        cm[mi][r] = x;
      }
    float alpha[2][4];
#pragma unroll
    for (int mi = 0; mi < 2; ++mi)
#pragma unroll
      for (int r = 0; r < 4; ++r) {
        const float nm = fmaxf(m_r[mi][r], cm[mi][r]);
        alpha[mi][r] = __expf(m_r[mi][r] - nm);
        m_r[mi][r] = nm;
        l_r[mi][r] *= alpha[mi][r];
      }
#pragma unroll
    for (int mi = 0; mi < 2; ++mi)
#pragma unroll
      for (int nd = 0; nd < 2; ++nd)
#pragma unroll
        for (int r = 0; r < 4; ++r) acc[mi][nd][r] *= alpha[mi][r];
#pragma unroll
    for (int mi = 0; mi < 2; ++mi)
#pragma unroll
      for (int ni = 0; ni < 4; ++ni)
#pragma unroll
        for (int r = 0; r < 4; ++r) {
          const float pv = __expf(sc[mi][ni][r] - m_r[mi][r]);
          l_r[mi][r] += pv;
          pw[(mi * 16 + fq * 4 + r) * 72 + ni * 16 + fm] = f2bf(pv);
        }
#pragma unroll
    for (int kc = 0; kc < 2; ++kc) {
      bf16x8 ap[2], bv[2];
#pragma unroll
      for (int mi = 0; mi < 2; ++mi)
        ap[mi] = *(const bf16x8*)&pw[(mi * 16 + fm) * 72 + kc * 32 + fq * 8];
#pragma unroll
      for (int nd = 0; nd < 2; ++nd)
        bv[nd] = *(const bf16x8*)&VTs[(nd * 16 + fm) * 388 + ch * 64 + kc * 32 + fq * 8];
#pragma unroll
      for (int mi = 0; mi < 2; ++mi)
#pragma unroll
        for (int nd = 0; nd < 2; ++nd)
          acc[mi][nd] = __builtin_amdgcn_mfma_f32_16x16x32_bf16(ap[mi], bv[nd], acc[mi][nd], 0, 0, 0);
    }
  }

  float linv[2][4];
#pragma unroll
  for (int mi = 0; mi < 2; ++mi)
#pragma unroll
    for (int r = 0; r < 4; ++r) {
      float x = l_r[mi][r];
      x += __shfl_xor(x, 1);
      x += __shfl_xor(x, 2);
      x += __shfl_xor(x, 4);
      x += __shfl_xor(x, 8);
      linv[mi][r] = 1.0f / x;
    }
#pragma unroll
  for (int mi = 0; mi < 2; ++mi)
#pragma unroll
    for (int nd = 0; nd < 2; ++nd)
#pragma unroll
      for (int r = 0; r < 4; ++r) {
        const long s = c * 128 + wid * 32 + mi * 16 + fq * 4 + r;
        CTX[((long)b * S_LEN + s) * HDIM + h * 32 + nd * 16 + fm] = f2bf(acc[mi][nd][r] * linv[mi][r]);
      }
}

// ---------------- conv1: 256x128 block, 9 taps (R7 structure, kept) ----------------
template <int APITCH, int NTAPS, int DIL, int NN>
__global__ __launch_bounds__(256, 2) void gemm_conv(
    const u16* __restrict__ Apad, const u16* __restrict__ BT, void* __restrict__ Outv,
    const float* __restrict__ bias,
    int SEGR, int BPITCH, int OSEGR, int OGUARD) {
  constexpr int AROWS = 256 + (NTAPS - 1) * DIL;
  constexpr int AOPS = (AROWS + 7) / 8;
  __shared__ __align__(16) u16 As[AOPS * 8 * 64];
  __shared__ __align__(16) u16 Bs2[2][128 * 64];
  const int tid = threadIdx.x;
  const int lane = tid & 63;
  const int wid = tid >> 6;
  const int wm = (wid & 1) * 128;
  const int wn = (wid >> 1) * 64;
  const int fm = lane & 15;
  const int fq = lane >> 4;
  const int t0 = blockIdx.x * 256;
  const int n0 = blockIdx.y * 128;

  const int seg = t0 >> 12;
  const long abase = (long)seg * SEGR + (t0 & (S_LEN - 1));
  const int srow = lane >> 3;
  const int cseg = (((lane & 7) ^ srow) << 3);

  f32x4 acc[8][4];
#pragma unroll
  for (int a = 0; a < 8; ++a)
#pragma unroll
    for (int b = 0; b < 4; ++b) acc[a][b] = (f32x4){0.f, 0.f, 0.f, 0.f};

  for (int k0 = 0; k0 < APITCH; k0 += 64) {
    for (int op = wid; op < AOPS; op += 4)
      glds16(Apad + (abase + op * 8 + srow) * APITCH + k0 + cseg, &As[op * 8 * 64]);
#pragma unroll
    for (int j = 0; j < 4; ++j)
      glds16(BT + (long)(n0 + wid * 32 + j * 8 + srow) * BPITCH + k0 + cseg,
             &Bs2[0][(wid * 32 + j * 8) * 64]);
    __syncthreads();
#pragma unroll
    for (int u = 0; u < NTAPS; ++u) {
      if (u + 1 < NTAPS) {
        const long bc = (long)(u + 1) * APITCH + k0;
#pragma unroll
        for (int j = 0; j < 4; ++j)
          glds16(BT + (long)(n0 + wid * 32 + j * 8 + srow) * BPITCH + bc + cseg,
                 &Bs2[(u + 1) & 1][(wid * 32 + j * 8) * 64]);
      }
      const int du = u * DIL;
      const u16* bsp = Bs2[u & 1];
#pragma unroll
      for (int kk = 0; kk < 2; ++kk) {
        const int g = kk * 4 + fq;
        bf16x8 af[8], bfv[4];
#pragma unroll
        for (int t = 0; t < 8; ++t) {
          const int ra = wm + t * 16 + fm + du;
          af[t] = *(const bf16x8*)&As[ra * 64 + ((g ^ (ra & 7)) << 3)];
        }
#pragma unroll
        for (int t = 0; t < 4; ++t) {
          const int rb = wn + t * 16 + fm;
          bfv[t] = *(const bf16x8*)&bsp[rb * 64 + ((g ^ (rb & 7)) << 3)];
        }
#pragma unroll
        for (int mi = 0; mi < 8; ++mi)
#pragma unroll
          for (int ni = 0; ni < 4; ++ni)
            acc[mi][ni] = __builtin_amdgcn_mfma_f32_16x16x32_bf16(af[mi], bfv[ni], acc[mi][ni], 0, 0, 0);
      }
      __syncthreads();
    }
  }

#pragma unroll
  for (int mi = 0; mi < 8; ++mi)
#pragma unroll
    for (int ni = 0; ni < 4; ++ni)
#pragma unroll
      for (int r = 0; r < 4; ++r) {
        const long trow = t0 + wm + mi * 16 + fq * 4 + r;
        const int col = n0 + wn + ni * 16 + fm;
        const long orow = (trow >> 12) * OSEGR + OGUARD + (trow & (S_LEN - 1));
        ((u16*)Outv)[orow * NN + col] = f2bf(gelu_f(acc[mi][ni][r] + bias[col]));
      }
}

// ---------------- conv2: R6 structure (128-tile, 3 taps/block, 3 blocks/CU) ----------------
__global__ __launch_bounds__(256) void gemm_conv_s(
    const u16* __restrict__ Apad, const u16* __restrict__ BT, float* __restrict__ Outv,
    int APITCH, int SEGR, int BPITCH, int ntaps, int dil, int N, long out_z_off) {
  __shared__ __align__(16) u16 As[144 * 64];
  __shared__ __align__(16) u16 Bs2[2][128 * 64];
  const int tid = threadIdx.x;
  const int lane = tid & 63;
  const int wid = tid >> 6;
  const int wm = (wid & 1) * 64;
  const int wn = (wid >> 1) * 64;
  const int fm = lane & 15;
  const int fq = lane >> 4;
  const int t0 = blockIdx.x * 128;
  const int n0 = blockIdx.y * 128;
  const int tap0 = blockIdx.z * ntaps;

  const int seg = t0 >> 12;
  const long abase = (long)seg * SEGR + (t0 & (S_LEN - 1)) + (long)tap0 * dil;
  const int aops = (128 + (ntaps - 1) * dil + 7) >> 3;

  const int srow = lane >> 3;
  const int cseg = (((lane & 7) ^ srow) << 3);

  f32x4 acc[4][4];
#pragma unroll
  for (int a = 0; a < 4; ++a)
#pragma unroll
    for (int b = 0; b < 4; ++b) acc[a][b] = (f32x4){0.f, 0.f, 0.f, 0.f};

  for (int k0 = 0; k0 < APITCH; k0 += 64) {
    for (int op = wid; op < aops; op += 4)
      glds16(Apad + (abase + op * 8 + srow) * APITCH + k0 + cseg, &As[op * 8 * 64]);
    {
      const long bc = (long)tap0 * APITCH + k0;
#pragma unroll
      for (int j = 0; j < 4; ++j)
        glds16(BT + (long)(n0 + wid * 32 + j * 8 + srow) * BPITCH + bc + cseg,
               &Bs2[0][(wid * 32 + j * 8) * 64]);
    }
    __syncthreads();
    for (int u = 0; u < ntaps; ++u) {
      if (u + 1 < ntaps) {
        const long bc = (long)(tap0 + u + 1) * APITCH + k0;
#pragma unroll
        for (int j = 0; j < 4; ++j)
          glds16(BT + (long)(n0 + wid * 32 + j * 8 + srow) * BPITCH + bc + cseg,
                 &Bs2[(u + 1) & 1][(wid * 32 + j * 8) * 64]);
      }
      const int du = u * dil;
      const u16* bsp = Bs2[u & 1];
#pragma unroll
      for (int kk = 0; kk < 2; ++kk) {
        const int g = kk * 4 + fq;
        bf16x8 af[4], bfv[4];
#pragma unroll
        for (int t = 0; t < 4; ++t) {
          const int ra = wm + t * 16 + fm + du;
          af[t] = *(const bf16x8*)&As[ra * 64 + ((g ^ (ra & 7)) << 3)];
          const int rb = wn + t * 16 + fm;
          bfv[t] = *(const bf16x8*)&bsp[rb * 64 + ((g ^ (rb & 7)) << 3)];
        }
#pragma unroll
        for (int mi = 0; mi < 4; ++mi)
#pragma unroll
          for (int ni = 0; ni < 4; ++ni)
            acc[mi][ni] = __builtin_amdgcn_mfma_f32_16x16x32_bf16(af[mi], bfv[ni], acc[mi][ni], 0, 0, 0);
      }
      __syncthreads();
    }
  }

#pragma unroll
  for (int mi = 0; mi < 4; ++mi)
#pragma unroll
    for (int ni = 0; ni < 4; ++ni)
#pragma unroll
      for (int r = 0; r < 4; ++r) {
        const long trow = t0 + wm + mi * 16 + fq * 4 + r;
        const int col = n0 + wn + ni * 16 + fm;
        (Outv + (long)blockIdx.z * out_z_off)[trow * N + col] = acc[mi][ni][r];
      }
}

// ---------------- final: out = x2 + gelu(P0+P1+P2 + b2)  (f32 out) ----------------
__global__ __launch_bounds__(256) void final_kernel(const float* __restrict__ x2, const float* __restrict__ P,
                                                    const float* __restrict__ b2, float* __restrict__ out) {
  const long i4 = ((long)blockIdx.x * 256 + threadIdx.x) * 4;
  const int c0 = (int)(i4 & (HDIM - 1));
  float4 xa = *(const float4*)(x2 + i4);
  float4 p0 = *(const float4*)(P + i4);
  float4 p1 = *(const float4*)(P + 4194304 + i4);
  float4 p2 = *(const float4*)(P + 8388608 + i4);
  const float pv[4] = {p0.x + p1.x + p2.x, p0.y + p1.y + p2.y, p0.z + p1.z + p2.z, p0.w + p1.w + p2.w};
  float4 o_;
  o_.x = xa.x + gelu_f(pv[0] + b2[c0 + 0]);
  o_.y = xa.y + gelu_f(pv[1] + b2[c0 + 1]);
  o_.z = xa.z + gelu_f(pv[2] + b2[c0 + 2]);
  o_.w = xa.w + gelu_f(pv[3] + b2[c0 + 3]);
  *(float4*)(out + i4) = o_;
}

extern "C" void kernel_launch(void* const* d_in, const int* in_sizes, int n_in,
                              void* d_out, int out_size, void* d_ws, size_t ws_size,
                              hipStream_t stream) {
  (void)in_sizes; (void)n_in; (void)out_size;
  const float* X    = (const float*)d_in[0];
  const float* dw_w = (const float*)d_in[1];
  const float* dw_b = (const float*)d_in[2];
  const float* pw_w = (const float*)d_in[3];
  const float* pw_b = (const float*)d_in[4];
  const float* Wq   = (const float*)d_in[5];
  const float* Wk   = (const float*)d_in[6];
  const float* Wv   = (const float*)d_in[7];
  const float* Wo   = (const float*)d_in[8];
  const float* rel  = (const float*)d_in[9];
  const float* ln1g = (const float*)d_in[10];
  const float* ln1b = (const float*)d_in[11];
  const float* ln2g = (const float*)d_in[12];
  const float* ln2b = (const float*)d_in[13];
  const float* w1   = (const float*)d_in[14];
  const float* b1   = (const float*)d_in[15];
  const float* w2   = (const float*)d_in[16];
  const float* b2   = (const float*)d_in[17];

  if (ws_size < 119537664) return;

  char* ws = (char*)d_ws;
  u16* WqT = (u16*)(ws + 0);
  u16* WkT = (u16*)(ws + 131072);
  u16* WvT = (u16*)(ws + 262144);
  u16* WoT = (u16*)(ws + 393216);
  u16* W1T = (u16*)(ws + 524288);
  u16* W2T = (u16*)(ws + 5242880);
  float* xn  = (float*)(ws + 10485760);   // 16 MiB, reused as x2
  float* x2  = xn;
  u16* gq  = (u16*)(ws + 27262976);
  u16* gk  = (u16*)(ws + 35651584);
  u16* gv  = (u16*)(ws + 44040192);
  u16* q   = (u16*)(ws + 52428800);       // q,k contiguous (o_z = 4M elems)
  u16* vt  = (u16*)(ws + 69206016);       // V^T [b][h][32][4096]
  u16* ctx = (u16*)(ws + 77594624);
  // phase-2 overlays (valid only after attn + Wo done)
  u16* f1p  = (u16*)(ws + 27262976);
  u16* xn2p = (u16*)(ws + 61341696);
  float* P  = (float*)(ws + 61341696);

  const float qscale = 0.17677669529663687f;
  ktranspose_all<<<4864, dim3(32, 8), 0, stream>>>(Wq, Wk, Wv, Wo, w1, w2,
      WqT, WkT, WvT, WoT, W1T, W2T, qscale);

  ln_kernel<0><<<4096, 256, 0, stream>>>(X, xn, ln1g, ln1b, 4096, 0, nullptr, nullptr);
  dwconv_qkv<<<4096, 256, 0, stream>>>(xn, gq, gk, gv, dw_w, dw_b, pw_w, pw_b);

  gemm_big<<<dim3(64, 2, 3), 256, 0, stream>>>(gq, WqT, q, vt,
      256, 256, 4194304, 65536, 4194304);

  attn_mfma<<<dim3(32, 8, 4), 256, 0, stream>>>(q, q + 4194304, vt, rel, ctx);

  gemm_wo<<<dim3(128, 2), 256, 0, stream>>>(ctx, WoT, x2, X, 256, 256);

  // LN2 + guard zeroing (guards ordered after phase-1 buffers die)
  ln_kernel<1><<<4228, 256, 0, stream>>>(x2, xn2p, ln2g, ln2b, 4104, 8,
      (uint4*)xn2p, (uint4*)f1p);

  // conv1: 256x128 tiles, 9 taps dil 1, K=256
  gemm_conv<256, 9, 1, 1024><<<dim3(64, 8), 256, 0, stream>>>(
      xn2p, W1T, f1p, b1, 4104, 2304, 4160, 64);

  // conv2: R6 structure — 128-tile, taps 3z..3z+2 (dil 8) -> fp32 partials, 3 blocks/CU
  gemm_conv_s<<<dim3(128, 2, 3), 256, 0, stream>>>(f1p, W2T, P,
      1024, 4160, 9216, 3, 8, 256, 4194304);

  final_kernel<<<4096, 256, 0, stream>>>(x2, P, b2, (float*)d_out);
}

// Round 9
// 380.868 us; speedup vs baseline: 1.0734x; 1.0219x over previous
//
#include <hip/hip_runtime.h>
#include <stdint.h>

typedef uint16_t u16;
typedef uint32_t u32;

typedef __attribute__((ext_vector_type(8))) short bf16x8;
typedef __attribute__((ext_vector_type(4))) float f32x4;

typedef __attribute__((address_space(1))) const u32 gas_u32;
typedef __attribute__((address_space(3))) u32 las_u32;

#define S_LEN 4096
#define HDIM  256
#define FFDIM 1024

__device__ __forceinline__ float bf2f(u16 u) { return __uint_as_float(((u32)u) << 16); }
__device__ __forceinline__ u16 f2bf(float f) {
  u32 x = __float_as_uint(f);
  return (u16)((x + 0x7fffu + ((x >> 16) & 1u)) >> 16);
}
__device__ __forceinline__ float gelu_f(float x) {
  return 0.5f * x * (1.0f + erff(x * 0.7071067811865475f));
}
__device__ __forceinline__ void glds16(const u16* g, u16* l) {
  __builtin_amdgcn_global_load_lds((gas_u32*)g, (las_u32*)l, 16, 0, 0);
}

// ---------------- fused front-end ----------------
// blocks [0,4864): weight transpose+cast (Wq..W2); blocks [4864,5888): LN1+dwconv+pw -> gq,gk,gv
__global__ __launch_bounds__(256) void front_kernel(
    const float* __restrict__ Wq, const float* __restrict__ Wk, const float* __restrict__ Wv,
    const float* __restrict__ Wo, const float* __restrict__ W1, const float* __restrict__ W2,
    u16* __restrict__ WqT, u16* __restrict__ WkT, u16* __restrict__ WvT,
    u16* __restrict__ WoT, u16* __restrict__ W1T, u16* __restrict__ W2T, float qscale,
    const float* __restrict__ X, u16* __restrict__ gq, u16* __restrict__ gk, u16* __restrict__ gv,
    const float* __restrict__ ln1g, const float* __restrict__ ln1b,
    const float* __restrict__ dw_w, const float* __restrict__ dw_b,
    const float* __restrict__ pw_w, const float* __restrict__ pw_b) {
  __shared__ u16 t[32][33];
  __shared__ float xnl[24 * 256];
  const int bid = blockIdx.x;
  const int tid = threadIdx.x;
  if (bid < 4864) {
    const float* in; u16* out; int K, N; float scale = 1.0f; int idx;
    if (bid < 256) {
      K = 256; N = 256; idx = bid & 63;
      const int w = bid >> 6;
      in = (w == 0) ? Wq : (w == 1) ? Wk : (w == 2) ? Wv : Wo;
      out = (w == 0) ? WqT : (w == 1) ? WkT : (w == 2) ? WvT : WoT;
      if (w == 0) scale = qscale;
    } else if (bid < 2560) {
      K = 2304; N = 1024; idx = bid - 256; in = W1; out = W1T;
    } else {
      K = 9216; N = 256; idx = bid - 2560; in = W2; out = W2T;
    }
    const int kt = K >> 5;
    const int k0 = (idx % kt) * 32, n0 = (idx / kt) * 32;
    const int tx = tid & 31, ty = tid >> 5;
#pragma unroll
    for (int i = ty; i < 32; i += 8) t[i][tx] = f2bf(in[(long)(k0 + i) * N + (n0 + tx)] * scale);
    __syncthreads();
#pragma unroll
    for (int i = ty; i < 32; i += 8) out[(long)(n0 + i) * K + (k0 + tx)] = t[tx][i];
    return;
  }
  // fused LN1 + dwconv + pw: 16 output rows per block, halo LN recompute
  const int ro = (bid - 4864) * 16;
  const int seg_lo = ro & ~(S_LEN - 1);
  const int lane = tid & 63;
  const int ri = tid >> 6;           // row-in-pass 0..3
  const int c0 = lane * 4;
  // phase 1: LN rows ro-4 .. ro+19 into xnl (zeros outside segment)
#pragma unroll
  for (int p = 0; p < 6; ++p) {
    const int h = ro - 4 + p * 4 + ri;
    float y[4] = {0.f, 0.f, 0.f, 0.f};
    if (h >= seg_lo && h < seg_lo + S_LEN) {
      float4 f = *(const float4*)(X + (long)h * HDIM + c0);
      float v[4] = {f.x, f.y, f.z, f.w};
      float s = v[0] + v[1] + v[2] + v[3];
#pragma unroll
      for (int o = 32; o > 0; o >>= 1) s += __shfl_xor(s, o);
      const float mean = s * (1.0f / 256.0f);
      float ss = 0.f;
#pragma unroll
      for (int j = 0; j < 4; ++j) { float d = v[j] - mean; ss += d * d; }
#pragma unroll
      for (int o = 32; o > 0; o >>= 1) ss += __shfl_xor(ss, o);
      const float inv_ = 1.0f / (sqrtf(ss * (1.0f / 255.0f)) + 1e-9f);
#pragma unroll
      for (int j = 0; j < 4; ++j) y[j] = ln1g[c0 + j] * (v[j] - mean) * inv_ + ln1b[c0 + j];
    }
    float4 o_; o_.x = y[0]; o_.y = y[1]; o_.z = y[2]; o_.w = y[3];
    *(float4*)&xnl[(p * 4 + ri) * 256 + c0] = o_;
  }
  __syncthreads();
  // phase 2: dwconv 9 taps + gelu + 3x pw-gelu
  const float b0 = dw_b[0];
  float wv[9];
#pragma unroll
  for (int q = 0; q < 9; ++q) wv[q] = dw_w[q];
  const float pwv[3] = {pw_w[0], pw_w[1], pw_w[2]};
  const float pbv[3] = {pw_b[0], pw_b[1], pw_b[2]};
  u16* outs[3] = {gq, gk, gv};
#pragma unroll
  for (int p = 0; p < 4; ++p) {
    const int lrow = p * 4 + ri;                 // output row = ro + lrow
    float a0 = b0, a1 = b0, a2 = b0, a3 = b0;
#pragma unroll
    for (int q = 0; q < 9; ++q) {
      const float w = wv[q];
      float4 xv = *(const float4*)&xnl[(lrow + q) * 256 + c0];
      a0 = fmaf(w, xv.x, a0); a1 = fmaf(w, xv.y, a1);
      a2 = fmaf(w, xv.z, a2); a3 = fmaf(w, xv.w, a3);
    }
    float h[4];
    h[0] = gelu_f(a0); h[1] = gelu_f(a1); h[2] = gelu_f(a2); h[3] = gelu_f(a3);
    const long orow = (long)(ro + lrow);
#pragma unroll
    for (int pp = 0; pp < 3; ++pp) {
      float y[4];
#pragma unroll
      for (int j = 0; j < 4; ++j) y[j] = gelu_f(fmaf(h[j], pwv[pp], pbv[pp]));
      uint2 o_;
      o_.x = (u32)f2bf(y[0]) | ((u32)f2bf(y[1]) << 16);
      o_.y = (u32)f2bf(y[2]) | ((u32)f2bf(y[3]) << 16);
      *(uint2*)(outs[pp] + orow * HDIM + c0) = o_;
    }
  }
}

// ---------------- layernorm2 (bf16 padded out) + guard zeroing ----------------
__global__ __launch_bounds__(256) void ln2_kernel(const float* __restrict__ inv, u16* __restrict__ outv,
                                                  const float* __restrict__ g, const float* __restrict__ bsh,
                                                  uint4* __restrict__ gx, uint4* __restrict__ gf) {
  const int tid = threadIdx.x;
  if (blockIdx.x >= 4096) {
    int t = (blockIdx.x - 4096) * 256 + tid;
    const uint4 z = {0u, 0u, 0u, 0u};
    if (t < 1024) {
      const int s = t >> 8, o = t & 255;
      gx[(long)s * 131328 + o] = z;
    } else {
      t -= 1024;
      if (t < 32768) {
        const int s = t >> 13, o = t & 8191;
        gf[(long)s * 532480 + o] = z;
      }
    }
    return;
  }
  const int lane = tid & 63;
  const long row = (long)blockIdx.x * 4 + (tid >> 6);
  const int c0 = lane * 4;
  float v[4];
  float4 f = *(const float4*)(inv + row * HDIM + c0);
  v[0] = f.x; v[1] = f.y; v[2] = f.z; v[3] = f.w;
  float s = v[0] + v[1] + v[2] + v[3];
#pragma unroll
  for (int o = 32; o > 0; o >>= 1) s += __shfl_xor(s, o);
  const float mean = s * (1.0f / 256.0f);
  float ss = 0.f;
#pragma unroll
  for (int j = 0; j < 4; ++j) { float d = v[j] - mean; ss += d * d; }
#pragma unroll
  for (int o = 32; o > 0; o >>= 1) ss += __shfl_xor(ss, o);
  const float inv_ = 1.0f / (sqrtf(ss * (1.0f / 255.0f)) + 1e-9f);
  float y[4];
#pragma unroll
  for (int j = 0; j < 4; ++j) y[j] = g[c0 + j] * (v[j] - mean) * inv_ + bsh[c0 + j];
  const long orow = (row >> 12) * 4104 + 8 + (row & (S_LEN - 1));
  uint2 o_;
  o_.x = (u32)f2bf(y[0]) | ((u32)f2bf(y[1]) << 16);
  o_.y = (u32)f2bf(y[2]) | ((u32)f2bf(y[3]) << 16);
  *(uint2*)(outv + orow * HDIM + c0) = o_;
}

// ---------------- 256x128 MFMA GEMM (QKV, z selects A/B/out; z==2 -> vt transpose) ----------------
__global__ __launch_bounds__(256) void gemm_big(
    const u16* __restrict__ A, const u16* __restrict__ BT, void* __restrict__ Outv,
    u16* __restrict__ vt, int KW, int N, long a_z, long b_z, long o_z) {
  __shared__ __align__(16) u16 As[256 * 64];
  __shared__ __align__(16) u16 Bs[128 * 64];
  const int tid = threadIdx.x;
  const int lane = tid & 63;
  const int wid = tid >> 6;
  const int wm = (wid & 1) * 128;
  const int wn = (wid >> 1) * 64;
  const int fm = lane & 15;
  const int fq = lane >> 4;
  const int t0 = blockIdx.x * 256;
  const int n0 = blockIdx.y * 128;
  A += (long)blockIdx.z * a_z;
  BT += (long)blockIdx.z * b_z;

  const int srow = lane >> 3;
  const int cseg = (((lane & 7) ^ srow) << 3);

  f32x4 acc[8][4];
#pragma unroll
  for (int a = 0; a < 8; ++a)
#pragma unroll
    for (int b = 0; b < 4; ++b) acc[a][b] = (f32x4){0.f, 0.f, 0.f, 0.f};

  for (int k0 = 0; k0 < KW; k0 += 64) {
    for (int op = wid; op < 32; op += 4)
      glds16(A + (long)(t0 + op * 8 + srow) * KW + k0 + cseg, &As[op * 8 * 64]);
#pragma unroll
    for (int j = 0; j < 4; ++j)
      glds16(BT + (long)(n0 + wid * 32 + j * 8 + srow) * KW + k0 + cseg,
             &Bs[(wid * 32 + j * 8) * 64]);
    __syncthreads();
#pragma unroll
    for (int kk = 0; kk < 2; ++kk) {
      const int g = kk * 4 + fq;
      bf16x8 af[8], bfv[4];
#pragma unroll
      for (int t = 0; t < 8; ++t) {
        const int ra = wm + t * 16 + fm;
        af[t] = *(const bf16x8*)&As[ra * 64 + ((g ^ (ra & 7)) << 3)];
      }
#pragma unroll
      for (int t = 0; t < 4; ++t) {
        const int rb = wn + t * 16 + fm;
        bfv[t] = *(const bf16x8*)&Bs[rb * 64 + ((g ^ (rb & 7)) << 3)];
      }
#pragma unroll
      for (int mi = 0; mi < 8; ++mi)
#pragma unroll
        for (int ni = 0; ni < 4; ++ni)
          acc[mi][ni] = __builtin_amdgcn_mfma_f32_16x16x32_bf16(af[mi], bfv[ni], acc[mi][ni], 0, 0, 0);
    }
    __syncthreads();
  }

#pragma unroll
  for (int mi = 0; mi < 8; ++mi)
#pragma unroll
    for (int ni = 0; ni < 4; ++ni) {
      if (blockIdx.z == 2) {
        const int col = n0 + wn + ni * 16 + fm;
        const int hh = col >> 5, dd = col & 31;
        const long trow0 = t0 + wm + mi * 16 + fq * 4;
        const long bb = trow0 >> 12;
        const int s0 = (int)(trow0 & (S_LEN - 1));
        uint2 o_;
        o_.x = (u32)f2bf(acc[mi][ni][0]) | ((u32)f2bf(acc[mi][ni][1]) << 16);
        o_.y = (u32)f2bf(acc[mi][ni][2]) | ((u32)f2bf(acc[mi][ni][3]) << 16);
        *(uint2*)(vt + ((bb * 8 + hh) * 32 + dd) * S_LEN + s0) = o_;
      } else {
#pragma unroll
        for (int r = 0; r < 4; ++r) {
          const long trow = t0 + wm + mi * 16 + fq * 4 + r;
          const int col = n0 + wn + ni * 16 + fm;
          ((u16*)Outv + (long)blockIdx.z * o_z)[trow * N + col] = f2bf(acc[mi][ni][r]);
        }
      }
    }
}

// ---------------- 128-tile MFMA GEMM (Wo + residual) ----------------
__global__ __launch_bounds__(256) void gemm_wo(
    const u16* __restrict__ A, const u16* __restrict__ BT, float* __restrict__ Outv,
    const float* __restrict__ residv, int KW, int N) {
  __shared__ __align__(16) u16 As[128 * 64];
  __shared__ __align__(16) u16 Bs[128 * 64];
  const int tid = threadIdx.x;
  const int lane = tid & 63;
  const int wid = tid >> 6;
  const int wm = (wid & 1) * 64;
  const int wn = (wid >> 1) * 64;
  const int fm = lane & 15;
  const int fq = lane >> 4;
  const int t0 = blockIdx.x * 128;
  const int n0 = blockIdx.y * 128;

  const int srow = lane >> 3;
  const int cseg = (((lane & 7) ^ srow) << 3);

  f32x4 acc[4][4];
#pragma unroll
  for (int a = 0; a < 4; ++a)
#pragma unroll
    for (int b = 0; b < 4; ++b) acc[a][b] = (f32x4){0.f, 0.f, 0.f, 0.f};

  u16* alb = &As[wid * 32 * 64];
  u16* blb = &Bs[wid * 32 * 64];

  for (int k0 = 0; k0 < KW; k0 += 64) {
    const u16* ag = A + (long)(t0 + wid * 32 + srow) * KW + k0 + cseg;
    const u16* bg = BT + (long)(n0 + wid * 32 + srow) * KW + k0 + cseg;
#pragma unroll
    for (int j = 0; j < 4; ++j) {
      glds16(ag + (long)(8 * j) * KW, alb + j * 8 * 64);
      glds16(bg + (long)(8 * j) * KW, blb + j * 8 * 64);
    }
    __syncthreads();
#pragma unroll
    for (int kk = 0; kk < 2; ++kk) {
      const int g = kk * 4 + fq;
      bf16x8 af[4], bfv[4];
#pragma unroll
      for (int t = 0; t < 4; ++t) {
        const int ra = wm + t * 16 + fm;
        af[t] = *(const bf16x8*)&As[ra * 64 + ((g ^ (ra & 7)) << 3)];
        const int rb = wn + t * 16 + fm;
        bfv[t] = *(const bf16x8*)&Bs[rb * 64 + ((g ^ (rb & 7)) << 3)];
      }
#pragma unroll
      for (int mi = 0; mi < 4; ++mi)
#pragma unroll
        for (int ni = 0; ni < 4; ++ni)
          acc[mi][ni] = __builtin_amdgcn_mfma_f32_16x16x32_bf16(af[mi], bfv[ni], acc[mi][ni], 0, 0, 0);
    }
    __syncthreads();
  }

#pragma unroll
  for (int mi = 0; mi < 4; ++mi)
#pragma unroll
    for (int ni = 0; ni < 4; ++ni)
#pragma unroll
      for (int r = 0; r < 4; ++r) {
        const long trow = t0 + wm + mi * 16 + fq * 4 + r;
        const int col = n0 + wn + ni * 16 + fm;
        Outv[trow * N + col] = acc[mi][ni][r] + residv[trow * N + col];
      }
}

// ---------------- MFMA flash attention (unchanged) ----------------
__global__ __launch_bounds__(256) void attn_mfma(const u16* __restrict__ Q, const u16* __restrict__ K,
                                                 const u16* __restrict__ VT, const float* __restrict__ rel,
                                                 u16* __restrict__ CTX) {
  __shared__ __align__(16) u16 Ks[384 * 36];
  __shared__ __align__(16) u16 VTs[32 * 388];
  __shared__ __align__(16) u16 Ps[4][32 * 72];
  __shared__ float bias_s[260];
  const int c = blockIdx.x, h = blockIdx.y, b = blockIdx.z;
  const int tid = threadIdx.x;
  const int lane = tid & 63, wid = tid >> 6;
  const int fm = lane & 15, fq = lane >> 4;
  const int j0 = c * 128 - 128;
  const long kvbase = ((long)b * S_LEN) * HDIM + h * 32;
  const long vtbase = (((long)b * 8 + h) * 32) * S_LEN;

  for (int idx = tid; idx < 384 * 4; idx += 256) {
    const int jj = idx >> 2, seg = (idx & 3) * 8;
    int j = j0 + jj; j = j < 0 ? 0 : (j > S_LEN - 1 ? S_LEN - 1 : j);
    uint4 kv = *(const uint4*)(K + kvbase + (long)j * HDIM + seg);
    *(uint4*)&Ks[jj * 36 + seg] = kv;
  }
#pragma unroll
  for (int p = 0; p < 6; ++p) {
    const int idx = p * 256 + tid;
    const int d = idx / 48, seg = idx - d * 48;
    int off = j0 + seg * 8; off = off < 0 ? 0 : (off > S_LEN - 8 ? S_LEN - 8 : off);
    uint4 vv = *(const uint4*)(VT + vtbase + (long)d * S_LEN + off);
    *(uint4*)&VTs[d * 388 + seg * 8] = vv;
  }
  for (int idx = tid; idx < 257; idx += 256) bias_s[idx] = rel[idx];
  __syncthreads();

  bf16x8 aq[2];
#pragma unroll
  for (int mi = 0; mi < 2; ++mi)
    aq[mi] = *(const bf16x8*)(Q + kvbase + (long)(c * 128 + wid * 32 + mi * 16 + fm) * HDIM + fq * 8);

  const int klo = (c == 0) ? 128 : 0;
  const int khi = (c == 31) ? 255 : 383;

  float m_r[2][4], l_r[2][4];
  f32x4 acc[2][2];
#pragma unroll
  for (int mi = 0; mi < 2; ++mi)
#pragma unroll
    for (int r = 0; r < 4; ++r) { m_r[mi][r] = -1e9f; l_r[mi][r] = 0.f; }
#pragma unroll
  for (int mi = 0; mi < 2; ++mi)
#pragma unroll
    for (int nd = 0; nd < 2; ++nd) acc[mi][nd] = (f32x4){0.f, 0.f, 0.f, 0.f};

  u16* pw = &Ps[wid][0];

  for (int ch = 0; ch < 6; ++ch) {
    f32x4 sc[2][4];
#pragma unroll
    for (int ni = 0; ni < 4; ++ni) {
      bf16x8 bk = *(const bf16x8*)&Ks[(ch * 64 + ni * 16 + fm) * 36 + fq * 8];
#pragma unroll
      for (int mi = 0; mi < 2; ++mi)
        sc[mi][ni] = __builtin_amdgcn_mfma_f32_16x16x32_bf16(aq[mi], bk, (f32x4){0.f, 0.f, 0.f, 0.f}, 0, 0, 0);
    }
    float cm[2][4];
#pragma unroll
    for (int mi = 0; mi < 2; ++mi)
#pragma unroll
      for (int r = 0; r < 4; ++r) cm[mi][r] = -1e9f;
#pragma unroll
    for (int mi = 0; mi < 2; ++mi)
#pragma unroll
      for (int ni = 0; ni < 4; ++ni) {
        const int keyloc = ch * 64 + ni * 16 + fm;
        const bool kval = (keyloc >= klo) && (keyloc <= khi);
#pragma unroll
        for (int r = 0; r < 4; ++r) {
          const int qloc = wid * 32 + mi * 16 + fq * 4 + r;
          const int rr = keyloc - qloc;
          const bool valid = kval && (rr >= 0) && (rr <= 256);
          const int rc = valid ? rr : 0;
          float vv = sc[mi][ni][r] + bias_s[rc];
          vv = valid ? vv : -1e9f;
          sc[mi][ni][r] = vv;
          cm[mi][r] = fmaxf(cm[mi][r], vv);
        }
      }
#pragma unroll
    for (int mi = 0; mi < 2; ++mi)
#pragma unroll
      for (int r = 0; r < 4; ++r) {
        float x = cm[mi][r];
        x = fmaxf(x, __shfl_xor(x, 1));
        x = fmaxf(x, __shfl_xor(x, 2));
        x = fmaxf(x, __shfl_xor(x, 4));
        x = fmaxf(x, __shfl_xor(x, 8));
        cm[mi][r] = x;
      }
    float alpha[2][4];
#pragma unroll
    for (int mi = 0; mi < 2; ++mi)
#pragma unroll
      for (int r = 0; r < 4; ++r) {
        const float nm = fmaxf(m_r[mi][r], cm[mi][r]);
        alpha[mi][r] = __expf(m_r[mi][r] - nm);
        m_r[mi][r] = nm;
        l_r[mi][r] *= alpha[mi][r];
      }
#pragma unroll
    for (int mi = 0; mi < 2; ++mi)
#pragma unroll
      for (int nd = 0; nd < 2; ++nd)
#pragma unroll
        for (int r = 0; r < 4; ++r) acc[mi][nd][r] *= alpha[mi][r];
#pragma unroll
    for (int mi = 0; mi < 2; ++mi)
#pragma unroll
      for (int ni = 0; ni < 4; ++ni)
#pragma unroll
        for (int r = 0; r < 4; ++r) {
          const float pv = __expf(sc[mi][ni][r] - m_r[mi][r]);
          l_r[mi][r] += pv;
          pw[(mi * 16 + fq * 4 + r) * 72 + ni * 16 + fm] = f2bf(pv);
        }
#pragma unroll
    for (int kc = 0; kc < 2; ++kc) {
      bf16x8 ap[2], bv[2];
#pragma unroll
      for (int mi = 0; mi < 2; ++mi)
        ap[mi] = *(const bf16x8*)&pw[(mi * 16 + fm) * 72 + kc * 32 + fq * 8];
#pragma unroll
      for (int nd = 0; nd < 2; ++nd)
        bv[nd] = *(const bf16x8*)&VTs[(nd * 16 + fm) * 388 + ch * 64 + kc * 32 + fq * 8];
#pragma unroll
      for (int mi = 0; mi < 2; ++mi)
#pragma unroll
        for (int nd = 0; nd < 2; ++nd)
          acc[mi][nd] = __builtin_amdgcn_mfma_f32_16x16x32_bf16(ap[mi], bv[nd], acc[mi][nd], 0, 0, 0);
    }
  }

  float linv[2][4];
#pragma unroll
  for (int mi = 0; mi < 2; ++mi)
#pragma unroll
    for (int r = 0; r < 4; ++r) {
      float x = l_r[mi][r];
      x += __shfl_xor(x, 1);
      x += __shfl_xor(x, 2);
      x += __shfl_xor(x, 4);
      x += __shfl_xor(x, 8);
      linv[mi][r] = 1.0f / x;
    }
#pragma unroll
  for (int mi = 0; mi < 2; ++mi)
#pragma unroll
    for (int nd = 0; nd < 2; ++nd)
#pragma unroll
      for (int r = 0; r < 4; ++r) {
        const long s = c * 128 + wid * 32 + mi * 16 + fq * 4 + r;
        CTX[((long)b * S_LEN + s) * HDIM + h * 32 + nd * 16 + fm] = f2bf(acc[mi][nd][r] * linv[mi][r]);
      }
}

// ---------------- conv1: 256x128 block, 9 taps, XCD-swizzled 1-D grid ----------------
template <int APITCH, int NTAPS, int DIL, int NN>
__global__ __launch_bounds__(256, 2) void gemm_conv(
    const u16* __restrict__ Apad, const u16* __restrict__ BT, void* __restrict__ Outv,
    const float* __restrict__ bias,
    int SEGR, int BPITCH, int OSEGR, int OGUARD) {
  constexpr int AROWS = 256 + (NTAPS - 1) * DIL;
  constexpr int AOPS = (AROWS + 7) / 8;
  __shared__ __align__(16) u16 As[AOPS * 8 * 64];
  __shared__ __align__(16) u16 Bs2[2][128 * 64];
  const int tid = threadIdx.x;
  const int lane = tid & 63;
  const int wid = tid >> 6;
  const int wm = (wid & 1) * 128;
  const int wn = (wid >> 1) * 64;
  const int fm = lane & 15;
  const int fq = lane >> 4;
  // XCD swizzle: n0 = low 3 bits (8 XCDs each own one B column-slice)
  const int t0 = (blockIdx.x >> 3) * 256;
  const int n0 = (blockIdx.x & 7) * 128;

  const int seg = t0 >> 12;
  const long abase = (long)seg * SEGR + (t0 & (S_LEN - 1));
  const int srow = lane >> 3;
  const int cseg = (((lane & 7) ^ srow) << 3);

  f32x4 acc[8][4];
#pragma unroll
  for (int a = 0; a < 8; ++a)
#pragma unroll
    for (int b = 0; b < 4; ++b) acc[a][b] = (f32x4){0.f, 0.f, 0.f, 0.f};

  for (int k0 = 0; k0 < APITCH; k0 += 64) {
    for (int op = wid; op < AOPS; op += 4)
      glds16(Apad + (abase + op * 8 + srow) * APITCH + k0 + cseg, &As[op * 8 * 64]);
#pragma unroll
    for (int j = 0; j < 4; ++j)
      glds16(BT + (long)(n0 + wid * 32 + j * 8 + srow) * BPITCH + k0 + cseg,
             &Bs2[0][(wid * 32 + j * 8) * 64]);
    __syncthreads();
#pragma unroll
    for (int u = 0; u < NTAPS; ++u) {
      if (u + 1 < NTAPS) {
        const long bc = (long)(u + 1) * APITCH + k0;
#pragma unroll
        for (int j = 0; j < 4; ++j)
          glds16(BT + (long)(n0 + wid * 32 + j * 8 + srow) * BPITCH + bc + cseg,
                 &Bs2[(u + 1) & 1][(wid * 32 + j * 8) * 64]);
      }
      const int du = u * DIL;
      const u16* bsp = Bs2[u & 1];
#pragma unroll
      for (int kk = 0; kk < 2; ++kk) {
        const int g = kk * 4 + fq;
        bf16x8 af[8], bfv[4];
#pragma unroll
        for (int t = 0; t < 8; ++t) {
          const int ra = wm + t * 16 + fm + du;
          af[t] = *(const bf16x8*)&As[ra * 64 + ((g ^ (ra & 7)) << 3)];
        }
#pragma unroll
        for (int t = 0; t < 4; ++t) {
          const int rb = wn + t * 16 + fm;
          bfv[t] = *(const bf16x8*)&bsp[rb * 64 + ((g ^ (rb & 7)) << 3)];
        }
#pragma unroll
        for (int mi = 0; mi < 8; ++mi)
#pragma unroll
          for (int ni = 0; ni < 4; ++ni)
            acc[mi][ni] = __builtin_amdgcn_mfma_f32_16x16x32_bf16(af[mi], bfv[ni], acc[mi][ni], 0, 0, 0);
      }
      __syncthreads();
    }
  }

#pragma unroll
  for (int mi = 0; mi < 8; ++mi)
#pragma unroll
    for (int ni = 0; ni < 4; ++ni)
#pragma unroll
      for (int r = 0; r < 4; ++r) {
        const long trow = t0 + wm + mi * 16 + fq * 4 + r;
        const int col = n0 + wn + ni * 16 + fm;
        const long orow = (trow >> 12) * OSEGR + OGUARD + (trow & (S_LEN - 1));
        ((u16*)Outv)[orow * NN + col] = f2bf(gelu_f(acc[mi][ni][r] + bias[col]));
      }
}

// ---------------- conv2: 128-tile, 3 taps/block, bf16 partials ----------------
__global__ __launch_bounds__(256) void gemm_conv_s(
    const u16* __restrict__ Apad, const u16* __restrict__ BT, u16* __restrict__ Outv,
    int APITCH, int SEGR, int BPITCH, int ntaps, int dil, int N, long out_z_off) {
  __shared__ __align__(16) u16 As[144 * 64];
  __shared__ __align__(16) u16 Bs2[2][128 * 64];
  const int tid = threadIdx.x;
  const int lane = tid & 63;
  const int wid = tid >> 6;
  const int wm = (wid & 1) * 64;
  const int wn = (wid >> 1) * 64;
  const int fm = lane & 15;
  const int fq = lane >> 4;
  const int t0 = blockIdx.x * 128;
  const int n0 = blockIdx.y * 128;
  const int tap0 = blockIdx.z * ntaps;

  const int seg = t0 >> 12;
  const long abase = (long)seg * SEGR + (t0 & (S_LEN - 1)) + (long)tap0 * dil;
  const int aops = (128 + (ntaps - 1) * dil + 7) >> 3;

  const int srow = lane >> 3;
  const int cseg = (((lane & 7) ^ srow) << 3);

  f32x4 acc[4][4];
#pragma unroll
  for (int a = 0; a < 4; ++a)
#pragma unroll
    for (int b = 0; b < 4; ++b) acc[a][b] = (f32x4){0.f, 0.f, 0.f, 0.f};

  for (int k0 = 0; k0 < APITCH; k0 += 64) {
    for (int op = wid; op < aops; op += 4)
      glds16(Apad + (abase + op * 8 + srow) * APITCH + k0 + cseg, &As[op * 8 * 64]);
    {
      const long bc = (long)tap0 * APITCH + k0;
#pragma unroll
      for (int j = 0; j < 4; ++j)
        glds16(BT + (long)(n0 + wid * 32 + j * 8 + srow) * BPITCH + bc + cseg,
               &Bs2[0][(wid * 32 + j * 8) * 64]);
    }
    __syncthreads();
    for (int u = 0; u < ntaps; ++u) {
      if (u + 1 < ntaps) {
        const long bc = (long)(tap0 + u + 1) * APITCH + k0;
#pragma unroll
        for (int j = 0; j < 4; ++j)
          glds16(BT + (long)(n0 + wid * 32 + j * 8 + srow) * BPITCH + bc + cseg,
                 &Bs2[(u + 1) & 1][(wid * 32 + j * 8) * 64]);
      }
      const int du = u * dil;
      const u16* bsp = Bs2[u & 1];
#pragma unroll
      for (int kk = 0; kk < 2; ++kk) {
        const int g = kk * 4 + fq;
        bf16x8 af[4], bfv[4];
#pragma unroll
        for (int t = 0; t < 4; ++t) {
          const int ra = wm + t * 16 + fm + du;
          af[t] = *(const bf16x8*)&As[ra * 64 + ((g ^ (ra & 7)) << 3)];
          const int rb = wn + t * 16 + fm;
          bfv[t] = *(const bf16x8*)&bsp[rb * 64 + ((g ^ (rb & 7)) << 3)];
        }
#pragma unroll
        for (int mi = 0; mi < 4; ++mi)
#pragma unroll
          for (int ni = 0; ni < 4; ++ni)
            acc[mi][ni] = __builtin_amdgcn_mfma_f32_16x16x32_bf16(af[mi], bfv[ni], acc[mi][ni], 0, 0, 0);
      }
      __syncthreads();
    }
  }

#pragma unroll
  for (int mi = 0; mi < 4; ++mi)
#pragma unroll
    for (int ni = 0; ni < 4; ++ni)
#pragma unroll
      for (int r = 0; r < 4; ++r) {
        const long trow = t0 + wm + mi * 16 + fq * 4 + r;
        const int col = n0 + wn + ni * 16 + fm;
        (Outv + (long)blockIdx.z * out_z_off)[trow * N + col] = f2bf(acc[mi][ni][r]);
      }
}

// ---------------- final: out = x2 + gelu(P0+P1+P2 + b2), P bf16 partials ----------------
__global__ __launch_bounds__(256) void final_kernel(const float* __restrict__ x2, const u16* __restrict__ P,
                                                    const float* __restrict__ b2, float* __restrict__ out) {
  const long i4 = ((long)blockIdx.x * 256 + threadIdx.x) * 4;
  const int c0 = (int)(i4 & (HDIM - 1));
  float4 xa = *(const float4*)(x2 + i4);
  uint2 u0 = *(const uint2*)(P + i4);
  uint2 u1 = *(const uint2*)(P + 4194304 + i4);
  uint2 u2 = *(const uint2*)(P + 8388608 + i4);
  float pv[4];
  pv[0] = bf2f((u16)(u0.x & 0xffffu)) + bf2f((u16)(u1.x & 0xffffu)) + bf2f((u16)(u2.x & 0xffffu));
  pv[1] = bf2f((u16)(u0.x >> 16)) + bf2f((u16)(u1.x >> 16)) + bf2f((u16)(u2.x >> 16));
  pv[2] = bf2f((u16)(u0.y & 0xffffu)) + bf2f((u16)(u1.y & 0xffffu)) + bf2f((u16)(u2.y & 0xffffu));
  pv[3] = bf2f((u16)(u0.y >> 16)) + bf2f((u16)(u1.y >> 16)) + bf2f((u16)(u2.y >> 16));
  float4 o_;
  o_.x = xa.x + gelu_f(pv[0] + b2[c0 + 0]);
  o_.y = xa.y + gelu_f(pv[1] + b2[c0 + 1]);
  o_.z = xa.z + gelu_f(pv[2] + b2[c0 + 2]);
  o_.w = xa.w + gelu_f(pv[3] + b2[c0 + 3]);
  *(float4*)(out + i4) = o_;
}

extern "C" void kernel_launch(void* const* d_in, const int* in_sizes, int n_in,
                              void* d_out, int out_size, void* d_ws, size_t ws_size,
                              hipStream_t stream) {
  (void)in_sizes; (void)n_in; (void)out_size;
  const float* X    = (const float*)d_in[0];
  const float* dw_w = (const float*)d_in[1];
  const float* dw_b = (const float*)d_in[2];
  const float* pw_w = (const float*)d_in[3];
  const float* pw_b = (const float*)d_in[4];
  const float* Wq   = (const float*)d_in[5];
  const float* Wk   = (const float*)d_in[6];
  const float* Wv   = (const float*)d_in[7];
  const float* Wo   = (const float*)d_in[8];
  const float* rel  = (const float*)d_in[9];
  const float* ln1g = (const float*)d_in[10];
  const float* ln1b = (const float*)d_in[11];
  const float* ln2g = (const float*)d_in[12];
  const float* ln2b = (const float*)d_in[13];
  const float* w1   = (const float*)d_in[14];
  const float* b1   = (const float*)d_in[15];
  const float* w2   = (const float*)d_in[16];
  const float* b2   = (const float*)d_in[17];

  if (ws_size < 119537664) return;

  char* ws = (char*)d_ws;
  u16* WqT = (u16*)(ws + 0);
  u16* WkT = (u16*)(ws + 131072);
  u16* WvT = (u16*)(ws + 262144);
  u16* WoT = (u16*)(ws + 393216);
  u16* W1T = (u16*)(ws + 524288);
  u16* W2T = (u16*)(ws + 5242880);
  float* x2  = (float*)(ws + 10485760);   // 16 MiB residual stream 2
  u16* gq  = (u16*)(ws + 27262976);
  u16* gk  = (u16*)(ws + 35651584);
  u16* gv  = (u16*)(ws + 44040192);
  u16* q   = (u16*)(ws + 52428800);       // q,k contiguous (o_z = 4M elems)
  u16* vt  = (u16*)(ws + 69206016);       // V^T [b][h][32][4096]
  u16* ctx = (u16*)(ws + 77594624);
  // phase-2 overlays (valid only after attn + Wo done)
  u16* f1p  = (u16*)(ws + 27262976);      // padded [4][4160][1024] bf16, ends at 61341696
  u16* xn2p = (u16*)(ws + 61341696);      // padded [4][4104][256] bf16
  u16* P    = (u16*)(ws + 61341696);      // 3 x 8 MiB bf16 partials (after conv1)

  const float qscale = 0.17677669529663687f;
  front_kernel<<<5888, 256, 0, stream>>>(Wq, Wk, Wv, Wo, w1, w2,
      WqT, WkT, WvT, WoT, W1T, W2T, qscale,
      X, gq, gk, gv, ln1g, ln1b, dw_w, dw_b, pw_w, pw_b);

  gemm_big<<<dim3(64, 2, 3), 256, 0, stream>>>(gq, WqT, q, vt,
      256, 256, 4194304, 65536, 4194304);

  attn_mfma<<<dim3(32, 8, 4), 256, 0, stream>>>(q, q + 4194304, vt, rel, ctx);

  gemm_wo<<<dim3(128, 2), 256, 0, stream>>>(ctx, WoT, x2, X, 256, 256);

  // LN2 + guard zeroing (phase-1 buffers dead)
  ln2_kernel<<<4228, 256, 0, stream>>>(x2, xn2p, ln2g, ln2b, (uint4*)xn2p, (uint4*)f1p);

  // conv1: 256x128 tiles, 9 taps dil 1, K=256, XCD-swizzled 1-D grid
  gemm_conv<256, 9, 1, 1024><<<512, 256, 0, stream>>>(
      xn2p, W1T, f1p, b1, 4104, 2304, 4160, 64);

  // conv2: 128-tile, taps 3z..3z+2 (dil 8) -> bf16 partials, 3 blocks/CU
  gemm_conv_s<<<dim3(128, 2, 3), 256, 0, stream>>>(f1p, W2T, P,
      1024, 4160, 9216, 3, 8, 256, 4194304);

  final_kernel<<<4096, 256, 0, stream>>>(x2, P, b2, (float*)d_out);
}